// Round 16
// baseline (183.500 us; speedup 1.0000x reference)
//
#include <hip/hip_runtime.h>

#define N_NODES 50000
#define N_EDGES 800000
#define F_IN    512
#define H_DIM   256
#define C_DIM   64
#define MPAD    50048   // 391 * 128

// sort geometry: bucket = row >> 8 (256 rows/bucket), chunk = 4096 edges
#define NB      196
#define NCHUNK  196     // ceil(800000/4096)
#define CHUNK   4096
#define BCAP    6144

typedef __bf16 bf16;
typedef __bf16 bf16x4 __attribute__((ext_vector_type(4)));
typedef __bf16 bf16x8 __attribute__((ext_vector_type(8)));
typedef float  f32x4  __attribute__((ext_vector_type(4)));
typedef unsigned int u32;
typedef unsigned long long u64;
typedef unsigned char u8;

__device__ __forceinline__ void gl_lds16(const void* g, void* l) {
    __builtin_amdgcn_global_load_lds(
        (const __attribute__((address_space(1))) u32*)g,
        (__attribute__((address_space(3))) u32*)l, 16, 0, 0);
}

__device__ __forceinline__ float unpack_val(u32 pk) {
    return __builtin_bit_cast(float, pk << 16);
}

// ---------------- prep: edge histogram (blocks 0..NCHUNK-1) + weight transpose ----------------

__global__ __launch_bounds__(1024) void prep_k(const int* __restrict__ rows,
                                               const float* __restrict__ W1,
                                               const float* __restrict__ W2,
                                               u32* __restrict__ G,
                                               bf16* __restrict__ W1t,
                                               bf16* __restrict__ W2t) {
    __shared__ u32 h[16 * NB];
    int bid = blockIdx.x, tid = threadIdx.x;
    if (bid < NCHUNK) {
        int wid = tid >> 6;
        for (int i = tid; i < 16 * NB; i += 1024) h[i] = 0;
        __syncthreads();
        int base = bid * CHUNK;
        int end = base + CHUNK; if (end > N_EDGES) end = N_EDGES;
        for (int e = base + tid; e < end; e += 1024)
            atomicAdd(&h[wid * NB + (rows[e] >> 8)], 1);
        __syncthreads();
        if (tid < NB) {
            u32 s = 0;
#pragma unroll
            for (int w = 0; w < 16; w++) s += h[w * NB + tid];
            G[tid * NCHUNK + bid] = s;
        }
    } else {
        int i = (bid - NCHUNK) * 1024 + tid;   // 144 blocks cover 147456 elems
        if (i < F_IN * H_DIM) {
            int k = i >> 8, n = i & 255;
            W1t[n * F_IN + k] = (bf16)W1[i];
        } else {
            int j = i - F_IN * H_DIM;
            if (j < H_DIM * C_DIM) {
                int k = j >> 6, n = j & 63;
                W2t[n * H_DIM + k] = (bf16)W2[j];
            }
        }
    }
}

// ---------------- merged: scatterB (blocks 0..NCHUNK-1) + GEMM1 (blocks NCHUNK..) ----------------
// GEMM1 now software-pipelines the A path: reg-prefetch next K-tile + counted-vmcnt barriers.

__global__ __launch_bounds__(512) void sg_k(const int* __restrict__ rows,
                                            const int* __restrict__ cols,
                                            const float* __restrict__ vals,
                                            const u32* __restrict__ G,
                                            u32* __restrict__ epack,
                                            u8* __restrict__ lrow,
                                            const float* __restrict__ A,
                                            const bf16* __restrict__ Bt,
                                            const float* __restrict__ bias,
                                            bf16* __restrict__ C) {
    __shared__ __attribute__((aligned(16))) char smem[49152];
    int bid = blockIdx.x, tid = threadIdx.x;
    int wid = tid >> 6, lane = tid & 63;

    if (bid < NCHUNK) {
        // ---- scatter part: direct atomic into bucket-grouped epack ----
        u32* cur = (u32*)smem;            // NB
        u32* wt  = (u32*)(smem + 1024);   // 4
        int c = bid;
        u32 tot = 0, pre = 0, incl = 0;
        if (tid < 256) {
            if (tid < NB) {
                for (int cc = 0; cc < NCHUNK; cc++) {
                    u32 v = G[tid * NCHUNK + cc];
                    tot += v;
                    if (cc < c) pre += v;
                }
            }
            incl = tot;
#pragma unroll
            for (int off = 1; off < 64; off <<= 1) {
                u32 u = __shfl_up(incl, off, 64);
                if (lane >= off) incl += u;
            }
            if (lane == 63) wt[wid] = incl;
        }
        __syncthreads();
        if (tid < 256) {
            u32 wpre = 0;
#pragma unroll
            for (int w = 0; w < 4; w++)
                if (w < wid) wpre += wt[w];
            if (tid < NB) cur[tid] = (wpre + incl - tot) + pre;
        }
        __syncthreads();
        int base = c * CHUNK;
        int end = base + CHUNK; if (end > N_EDGES) end = N_EDGES;
        for (int e = base + tid; e < end; e += 512) {
            int r = rows[e];
            unsigned short vb = __builtin_bit_cast(unsigned short, (bf16)vals[e]);
            u32 pk = ((u32)cols[e] << 16) | (u32)vb;
            u32 p = atomicAdd(&cur[r >> 8], 1);
            epack[p] = pk;
            lrow[p] = (u8)(r & 255);
        }
        return;
    }

    // ---- gemm1 part: BM=128, BN=256, BK=64, XOR-swizzled LDS, A-prefetch pipeline ----
    constexpr int BM = 128, BK = 64;
    bf16* As = (bf16*)smem;            // 16 KB
    bf16* Bs = (bf16*)(smem + 16384);  // 32 KB
    int wr = wid >> 2, wc = wid & 3;
    int l15 = lane & 15, hi = lane >> 4;
    int sw = l15 & 7;
    int bm = bid - NCHUNK;

    // per-thread A staging coordinates (2 chunks of 16B-f32 pairs)
    int ch0 = tid, ch1 = 512 + tid;
    int row0_ = ch0 >> 3, kc0 = ch0 & 7;
    int row1_ = ch1 >> 3, kc1 = ch1 & 7;
    int ar0 = bm * BM + row0_; if (ar0 >= N_NODES) ar0 = N_NODES - 1;
    int ar1 = bm * BM + row1_; if (ar1 >= N_NODES) ar1 = N_NODES - 1;
    const float* a0p = A + (size_t)ar0 * F_IN + kc0 * 8;
    const float* a1p = A + (size_t)ar1 * F_IN + kc1 * 8;

    f32x4 acc[4][4];
#pragma unroll
    for (int m = 0; m < 4; m++)
#pragma unroll
        for (int n = 0; n < 4; n++) acc[m][n] = (f32x4){0.f, 0.f, 0.f, 0.f};

    // prologue: prefetch A for kt=0
    f32x4 pa00 = *(const f32x4*)(a0p + 0);
    f32x4 pa01 = *(const f32x4*)(a0p + 4);
    f32x4 pa10 = *(const f32x4*)(a1p + 0);
    f32x4 pa11 = *(const f32x4*)(a1p + 4);

#pragma unroll
    for (int it = 0; it < F_IN / BK; it++) {
        int kt = it * BK;
        // issue B gl_lds for kt (4 ops; these must complete before barrier-1 passes)
#pragma unroll
        for (int j = 0; j < 4; j++) {
            int ch = j * 512 + tid;
            int row = ch >> 3, kc = ch & 7;
            int kcs = kc ^ (row & 7);
            gl_lds16(Bt + (size_t)row * F_IN + kt + kcs * 8,
                     &Bs[(j * 512 + wid * 64) * 8]);
        }
        // convert current A regs -> swizzled LDS (compiler waits the pa loads)
        {
            bf16x8 o;
            o[0] = (bf16)pa00[0]; o[1] = (bf16)pa00[1]; o[2] = (bf16)pa00[2]; o[3] = (bf16)pa00[3];
            o[4] = (bf16)pa01[0]; o[5] = (bf16)pa01[1]; o[6] = (bf16)pa01[2]; o[7] = (bf16)pa01[3];
            *(bf16x8*)&As[row0_ * BK + (kc0 ^ (row0_ & 7)) * 8] = o;
            bf16x8 o2;
            o2[0] = (bf16)pa10[0]; o2[1] = (bf16)pa10[1]; o2[2] = (bf16)pa10[2]; o2[3] = (bf16)pa10[3];
            o2[4] = (bf16)pa11[0]; o2[5] = (bf16)pa11[1]; o2[6] = (bf16)pa11[2]; o2[7] = (bf16)pa11[3];
            *(bf16x8*)&As[row1_ * BK + (kc1 ^ (row1_ & 7)) * 8] = o2;
        }
        // prefetch A for next K-tile (wraps to 0 on last iter; kept alive below)
        {
            int ktn = (kt + BK < F_IN) ? kt + BK : 0;
            pa00 = *(const f32x4*)(a0p + ktn);
            pa01 = *(const f32x4*)(a0p + ktn + 4);
            pa10 = *(const f32x4*)(a1p + ktn);
            pa11 = *(const f32x4*)(a1p + ktn + 4);
        }
        // barrier-1: wait B gl_lds (4 oldest) + LDS writes; leave 4 A-prefetch in flight
        asm volatile("s_waitcnt vmcnt(4) lgkmcnt(0)" ::: "memory");
        __builtin_amdgcn_s_barrier();

        bf16x8 afr[2][4], bfr[2][4];
#pragma unroll
        for (int kk = 0; kk < 2; kk++) {
            int c = (kk * 4 + hi) ^ sw;
#pragma unroll
            for (int m = 0; m < 4; m++)
                afr[kk][m] = *(const bf16x8*)&As[(wr * 64 + m * 16 + l15) * BK + c * 8];
#pragma unroll
            for (int n = 0; n < 4; n++)
                bfr[kk][n] = *(const bf16x8*)&Bs[(wc * 64 + n * 16 + l15) * BK + c * 8];
        }
#pragma unroll
        for (int kk = 0; kk < 2; kk++)
#pragma unroll
            for (int m = 0; m < 4; m++)
#pragma unroll
                for (int n = 0; n < 4; n++)
                    acc[m][n] = __builtin_amdgcn_mfma_f32_16x16x32_bf16(
                        afr[kk][m], bfr[kk][n], acc[m][n], 0, 0, 0);
        // barrier-2: LDS reads done before next overwrite; do NOT drain vmcnt
        asm volatile("s_waitcnt lgkmcnt(0)" ::: "memory");
        __builtin_amdgcn_s_barrier();
    }
    // keep the final (unused) prefetch loads live so vmcnt counts stay correct
    asm volatile("" :: "v"(pa00[0]), "v"(pa01[0]), "v"(pa10[0]), "v"(pa11[0]));

#pragma unroll
    for (int m = 0; m < 4; m++) {
        int row0 = bm * BM + wr * 64 + m * 16 + hi * 4;
#pragma unroll
        for (int n = 0; n < 4; n++) {
            int col = wc * 64 + n * 16 + l15;
            float bz = bias[col];
#pragma unroll
            for (int r = 0; r < 4; r++) {
                int row = row0 + r;
                if (row < N_NODES)
                    C[(size_t)row * H_DIM + col] = (bf16)(acc[m][n][r] + bz);
            }
        }
    }
}

// ---------------- sortC: in-LDS counting sort within bucket ----------------

__global__ __launch_bounds__(256) void sortC_k(u32* __restrict__ epack,
                                               const u8* __restrict__ lrow,
                                               const u32* __restrict__ G,
                                               int* __restrict__ starts) {
    __shared__ u32 edat[BCAP];
    __shared__ u32 sdat[BCAP];
    __shared__ u8  erow[BCAP];
    __shared__ u32 h[4 * 256];
    __shared__ u32 cur[256];
    __shared__ u32 wt1[4], wt2[4];
    __shared__ u32 sh_s, sh_n;
    int b = blockIdx.x, tid = threadIdx.x, wid = tid >> 6, lane = tid & 63;

    u32 btot = 0;
    if (tid < NB)
        for (int cc = 0; cc < NCHUNK; cc++) btot += G[tid * NCHUNK + cc];
    u32 bincl = btot;
#pragma unroll
    for (int off = 1; off < 64; off <<= 1) {
        u32 u = __shfl_up(bincl, off, 64);
        if (lane >= off) bincl += u;
    }
    if (lane == 63) wt1[wid] = bincl;
    __syncthreads();
    u32 bwpre = 0;
#pragma unroll
    for (int w = 0; w < 4; w++)
        if (w < wid) bwpre += wt1[w];
    if (tid == b) { sh_s = bwpre + bincl - btot; sh_n = btot; }
    __syncthreads();
    int s = (int)sh_s;
    int n = (int)sh_n;
    if (n > BCAP) n = BCAP;

    for (int i = tid; i < n; i += 256) { edat[i] = epack[s + i]; erow[i] = lrow[s + i]; }
    for (int i = tid; i < 1024; i += 256) h[i] = 0;
    __syncthreads();
    for (int i = tid; i < n; i += 256) atomicAdd(&h[wid * 256 + erow[i]], 1);
    __syncthreads();
    u32 tot = h[tid] + h[256 + tid] + h[512 + tid] + h[768 + tid];
    u32 incl = tot;
#pragma unroll
    for (int off = 1; off < 64; off <<= 1) {
        u32 u = __shfl_up(incl, off, 64);
        if (lane >= off) incl += u;
    }
    if (lane == 63) wt2[wid] = incl;
    __syncthreads();
    u32 wpre = 0;
#pragma unroll
    for (int w = 0; w < 4; w++)
        if (w < wid) wpre += wt2[w];
    u32 excl = wpre + incl - tot;
    cur[tid] = excl;
    int grow = b * 256 + tid;
    if (grow < N_NODES) starts[grow] = s + (int)excl;
    if (b == 0 && tid == 0) starts[N_NODES] = N_EDGES;
    __syncthreads();
    for (int i = tid; i < n; i += 256) {
        u32 p = atomicAdd(&cur[erow[i]], 1);
        sdat[p] = edat[i];
    }
    __syncthreads();
    for (int i = tid; i < n; i += 256) epack[s + i] = sdat[i];
}

// ---------------- GEMM2: C[M,64] = x16[M,256] @ W2t^T + b2, XOR-swizzled LDS ----------------

__global__ __launch_bounds__(256) void gemm2_k(const bf16* __restrict__ A,
                                               const bf16* __restrict__ Bt,
                                               const float* __restrict__ bias,
                                               bf16* __restrict__ C) {
    constexpr int BM = 128, BK = 64;
    __shared__ bf16 As[BM * BK];
    __shared__ bf16 Bs[64 * BK];

    int tid = threadIdx.x;
    int wid = tid >> 6, lane = tid & 63;
    int wr = wid >> 1, wc = wid & 1;
    int l15 = lane & 15, hi = lane >> 4;
    int sw = l15 & 7;
    int bm = blockIdx.x;

    f32x4 acc[4][2];
#pragma unroll
    for (int m = 0; m < 4; m++)
#pragma unroll
        for (int n = 0; n < 2; n++) acc[m][n] = (f32x4){0.f, 0.f, 0.f, 0.f};

    for (int kt = 0; kt < H_DIM; kt += BK) {
#pragma unroll
        for (int j = 0; j < 4; j++) {
            int ch = j * 256 + tid;
            int row = ch >> 3, kc = ch & 7;
            int kcs = kc ^ (row & 7);
            gl_lds16(A + (size_t)(bm * BM + row) * H_DIM + kt + kcs * 8,
                     &As[(j * 256 + wid * 64) * 8]);
        }
#pragma unroll
        for (int j = 0; j < 2; j++) {
            int ch = j * 256 + tid;
            int row = ch >> 3, kc = ch & 7;
            int kcs = kc ^ (row & 7);
            gl_lds16(Bt + (size_t)row * H_DIM + kt + kcs * 8,
                     &Bs[(j * 256 + wid * 64) * 8]);
        }
        __syncthreads();

        bf16x8 afr[2][4], bfr[2][2];
#pragma unroll
        for (int kk = 0; kk < 2; kk++) {
            int c = (kk * 4 + hi) ^ sw;
#pragma unroll
            for (int m = 0; m < 4; m++)
                afr[kk][m] = *(const bf16x8*)&As[(wr * 64 + m * 16 + l15) * BK + c * 8];
#pragma unroll
            for (int n = 0; n < 2; n++)
                bfr[kk][n] = *(const bf16x8*)&Bs[(wc * 32 + n * 16 + l15) * BK + c * 8];
        }
#pragma unroll
        for (int kk = 0; kk < 2; kk++)
#pragma unroll
            for (int m = 0; m < 4; m++)
#pragma unroll
                for (int n = 0; n < 2; n++)
                    acc[m][n] = __builtin_amdgcn_mfma_f32_16x16x32_bf16(
                        afr[kk][m], bfr[kk][n], acc[m][n], 0, 0, 0);
        __syncthreads();
    }

#pragma unroll
    for (int m = 0; m < 4; m++) {
        int row0 = bm * BM + wr * 64 + m * 16 + hi * 4;
#pragma unroll
        for (int n = 0; n < 2; n++) {
            int col = wc * 32 + n * 16 + l15;
            float bz = bias[col];
#pragma unroll
            for (int r = 0; r < 4; r++) {
                int row = row0 + r;
                if (row < N_NODES)
                    C[(size_t)row * C_DIM + col] = (bf16)(acc[m][n][r] + bz);
            }
        }
    }
}

// ---------------- SpMM1: row-per-wave, 8 gathers in flight, NT streams ----------------
// Parked at line-BW roofline: 800K edges x 8 lines = 410 MB @ ~6.6 TB/s ~ 62 us.

__global__ __launch_bounds__(256) void spmm1_k(const int* __restrict__ starts,
                                               const u32* __restrict__ epack,
                                               const bf16* __restrict__ s1,
                                               bf16* __restrict__ x16) {
    int wid = threadIdx.x >> 6, lane = threadIdx.x & 63;
    int row = blockIdx.x * 4 + wid;
    if (row >= N_NODES) return;
    int s = starts[row], e = starts[row + 1];
    f32x4 acc = (f32x4){0.f, 0.f, 0.f, 0.f};
    const bf16* s1l = s1 + lane * 4;
    int p = s;
    for (; p + 8 <= e; p += 8) {
        u32 k0 = __builtin_nontemporal_load(epack + p);
        u32 k1 = __builtin_nontemporal_load(epack + p + 1);
        u32 k2 = __builtin_nontemporal_load(epack + p + 2);
        u32 k3 = __builtin_nontemporal_load(epack + p + 3);
        u32 k4 = __builtin_nontemporal_load(epack + p + 4);
        u32 k5 = __builtin_nontemporal_load(epack + p + 5);
        u32 k6 = __builtin_nontemporal_load(epack + p + 6);
        u32 k7 = __builtin_nontemporal_load(epack + p + 7);
        bf16x4 g0 = *(const bf16x4*)(s1l + (size_t)(k0 >> 16) * H_DIM);
        bf16x4 g1 = *(const bf16x4*)(s1l + (size_t)(k1 >> 16) * H_DIM);
        bf16x4 g2 = *(const bf16x4*)(s1l + (size_t)(k2 >> 16) * H_DIM);
        bf16x4 g3 = *(const bf16x4*)(s1l + (size_t)(k3 >> 16) * H_DIM);
        bf16x4 g4 = *(const bf16x4*)(s1l + (size_t)(k4 >> 16) * H_DIM);
        bf16x4 g5 = *(const bf16x4*)(s1l + (size_t)(k5 >> 16) * H_DIM);
        bf16x4 g6 = *(const bf16x4*)(s1l + (size_t)(k6 >> 16) * H_DIM);
        bf16x4 g7 = *(const bf16x4*)(s1l + (size_t)(k7 >> 16) * H_DIM);
        float v0 = unpack_val(k0), v1 = unpack_val(k1), v2 = unpack_val(k2), v3 = unpack_val(k3);
        float v4 = unpack_val(k4), v5 = unpack_val(k5), v6 = unpack_val(k6), v7 = unpack_val(k7);
#pragma unroll
        for (int j = 0; j < 4; j++)
            acc[j] += v0 * (float)g0[j] + v1 * (float)g1[j] +
                      v2 * (float)g2[j] + v3 * (float)g3[j] +
                      v4 * (float)g4[j] + v5 * (float)g5[j] +
                      v6 * (float)g6[j] + v7 * (float)g7[j];
    }
    for (; p < e; ++p) {
        u32 k = __builtin_nontemporal_load(epack + p);
        float v = unpack_val(k);
        bf16x4 g = *(const bf16x4*)(s1l + (size_t)(k >> 16) * H_DIM);
#pragma unroll
        for (int j = 0; j < 4; j++) acc[j] += v * (float)g[j];
    }
    bf16x4 o;
#pragma unroll
    for (int j = 0; j < 4; j++) o[j] = (bf16)fmaxf(acc[j], 0.f);
    u64 bits = __builtin_bit_cast(u64, o);
    __builtin_nontemporal_store(bits, (u64*)(x16 + (size_t)row * H_DIM + lane * 4));
}

// ---------------- SpMM2 + log_softmax fused: D=64, lane = class, 8-wide, NT ----------------

__global__ __launch_bounds__(256) void spmm2_sm_k(const int* __restrict__ starts,
                                                  const u32* __restrict__ epack,
                                                  const bf16* __restrict__ s2,
                                                  float* __restrict__ out) {
    int wid = threadIdx.x >> 6, lane = threadIdx.x & 63;
    int row = blockIdx.x * 4 + wid;
    if (row >= N_NODES) return;
    int s = starts[row], e = starts[row + 1];
    float acc = 0.f;
    int p = s;
    for (; p + 8 <= e; p += 8) {
        u32 k0 = __builtin_nontemporal_load(epack + p);
        u32 k1 = __builtin_nontemporal_load(epack + p + 1);
        u32 k2 = __builtin_nontemporal_load(epack + p + 2);
        u32 k3 = __builtin_nontemporal_load(epack + p + 3);
        u32 k4 = __builtin_nontemporal_load(epack + p + 4);
        u32 k5 = __builtin_nontemporal_load(epack + p + 5);
        u32 k6 = __builtin_nontemporal_load(epack + p + 6);
        u32 k7 = __builtin_nontemporal_load(epack + p + 7);
        float g0 = (float)s2[(size_t)(k0 >> 16) * C_DIM + lane];
        float g1 = (float)s2[(size_t)(k1 >> 16) * C_DIM + lane];
        float g2 = (float)s2[(size_t)(k2 >> 16) * C_DIM + lane];
        float g3 = (float)s2[(size_t)(k3 >> 16) * C_DIM + lane];
        float g4 = (float)s2[(size_t)(k4 >> 16) * C_DIM + lane];
        float g5 = (float)s2[(size_t)(k5 >> 16) * C_DIM + lane];
        float g6 = (float)s2[(size_t)(k6 >> 16) * C_DIM + lane];
        float g7 = (float)s2[(size_t)(k7 >> 16) * C_DIM + lane];
        acc += unpack_val(k0) * g0 + unpack_val(k1) * g1 +
               unpack_val(k2) * g2 + unpack_val(k3) * g3 +
               unpack_val(k4) * g4 + unpack_val(k5) * g5 +
               unpack_val(k6) * g6 + unpack_val(k7) * g7;
    }
    for (; p < e; ++p) {
        u32 k = __builtin_nontemporal_load(epack + p);
        acc += unpack_val(k) * (float)s2[(size_t)(k >> 16) * C_DIM + lane];
    }
    float mx = acc;
#pragma unroll
    for (int off = 32; off >= 1; off >>= 1) mx = fmaxf(mx, __shfl_xor(mx, off, 64));
    float ex = expf(acc - mx);
    float se = ex;
#pragma unroll
    for (int off = 32; off >= 1; off >>= 1) se += __shfl_xor(se, off, 64);
    __builtin_nontemporal_store((acc - mx) - logf(se),
                                out + (size_t)row * C_DIM + lane);
}

// ---------------- launch ----------------

extern "C" void kernel_launch(void* const* d_in, const int* in_sizes, int n_in,
                              void* d_out, int out_size, void* d_ws, size_t ws_size,
                              hipStream_t stream) {
    const float* nf   = (const float*)d_in[0];
    const int*   rows = (const int*)d_in[1];
    const int*   cols = (const int*)d_in[2];
    const float* vals = (const float*)d_in[3];
    const float* W1   = (const float*)d_in[4];
    const float* b1   = (const float*)d_in[5];
    const float* W2   = (const float*)d_in[6];
    const float* b2   = (const float*)d_in[7];
    float* out = (float*)d_out;

    char* w = (char*)d_ws;
    auto alloc = [&](size_t b) { void* p = (void*)w; w += (b + 255) & ~(size_t)255; return p; };

    bf16* x16  = (bf16*)alloc((size_t)MPAD * H_DIM * 2);
    bf16* sup1 = (bf16*)alloc((size_t)N_NODES * H_DIM * 2);
    bf16* sup2 = sup1;   // aliases sup1 (dead by then)
    bf16* W1t = (bf16*)alloc((size_t)H_DIM * F_IN * 2);
    bf16* W2t = (bf16*)alloc((size_t)C_DIM * H_DIM * 2);
    int* starts = (int*)alloc((size_t)(N_NODES + 1) * 4);
    u32* G      = (u32*)alloc((size_t)NB * NCHUNK * 4);
    u32* epack  = (u32*)alloc((size_t)N_EDGES * 4);
    u8*  lrow   = (u8*)alloc((size_t)N_EDGES);

    // 1) hist + weight transpose (independent, fused)
    prep_k<<<NCHUNK + 144, 1024, 0, stream>>>(rows, W1, W2, G, W1t, W2t);
    // 2) scatter (196 blocks) + layer-1 GEMM (391 blocks, A-prefetch pipeline)
    sg_k<<<NCHUNK + MPAD / 128, 512, 0, stream>>>(rows, cols, vals, G, epack, lrow,
                                                  nf, W1t, b1, sup1);
    // 3) in-bucket sort
    sortC_k<<<NB, 256, 0, stream>>>(epack, lrow, G, starts);
    // 4) aggregate layer 1
    spmm1_k<<<(N_NODES + 3) / 4, 256, 0, stream>>>(starts, epack, sup1, x16);
    // 5) layer 2 GEMM (swizzled LDS)
    gemm2_k<<<MPAD / 128, 256, 0, stream>>>(x16, W2t, b2, sup2);
    // 6) aggregate layer 2 + log_softmax
    spmm2_sm_k<<<(N_NODES + 3) / 4, 256, 0, stream>>>(starts, epack, sup2, out);

    (void)in_sizes; (void)n_in; (void)out_size; (void)ws_size;
}

// Round 17
// 173.131 us; speedup vs baseline: 1.0599x; 1.0599x over previous
//
#include <hip/hip_runtime.h>

#define N_NODES 50000
#define N_EDGES 800000
#define F_IN    512
#define H_DIM   256
#define C_DIM   64
#define MPAD    50048   // 391 * 128

// sort geometry: bucket = row >> 8 (256 rows/bucket), chunk = 4096 edges
#define NB      196
#define NCHUNK  196     // ceil(800000/4096)
#define CHUNK   4096
#define BCAP    6144

typedef __bf16 bf16;
typedef __bf16 bf16x4 __attribute__((ext_vector_type(4)));
typedef __bf16 bf16x8 __attribute__((ext_vector_type(8)));
typedef float  f32x4  __attribute__((ext_vector_type(4)));
typedef unsigned int u32;
typedef unsigned long long u64;
typedef unsigned char u8;

__device__ __forceinline__ void gl_lds16(const void* g, void* l) {
    __builtin_amdgcn_global_load_lds(
        (const __attribute__((address_space(1))) u32*)g,
        (__attribute__((address_space(3))) u32*)l, 16, 0, 0);
}

__device__ __forceinline__ float unpack_val(u32 pk) {
    return __builtin_bit_cast(float, pk << 16);
}

// ---------------- prep: edge histogram (blocks 0..NCHUNK-1) + weight transpose ----------------

__global__ __launch_bounds__(1024) void prep_k(const int* __restrict__ rows,
                                               const float* __restrict__ W1,
                                               const float* __restrict__ W2,
                                               u32* __restrict__ G,
                                               bf16* __restrict__ W1t,
                                               bf16* __restrict__ W2t) {
    __shared__ u32 h[16 * NB];
    int bid = blockIdx.x, tid = threadIdx.x;
    if (bid < NCHUNK) {
        int wid = tid >> 6;
        for (int i = tid; i < 16 * NB; i += 1024) h[i] = 0;
        __syncthreads();
        int base = bid * CHUNK;
        int end = base + CHUNK; if (end > N_EDGES) end = N_EDGES;
        for (int e = base + tid; e < end; e += 1024)
            atomicAdd(&h[wid * NB + (rows[e] >> 8)], 1);
        __syncthreads();
        if (tid < NB) {
            u32 s = 0;
#pragma unroll
            for (int w = 0; w < 16; w++) s += h[w * NB + tid];
            G[tid * NCHUNK + bid] = s;
        }
    } else {
        int i = (bid - NCHUNK) * 1024 + tid;   // 144 blocks cover 147456 elems
        if (i < F_IN * H_DIM) {
            int k = i >> 8, n = i & 255;
            W1t[n * F_IN + k] = (bf16)W1[i];
        } else {
            int j = i - F_IN * H_DIM;
            if (j < H_DIM * C_DIM) {
                int k = j >> 6, n = j & 63;
                W2t[n * H_DIM + k] = (bf16)W2[j];
            }
        }
    }
}

// ---------------- merged: scatterB (blocks 0..NCHUNK-1) + GEMM1 (blocks NCHUNK..) ----------------
// Scatter: ONE u64 store per edge (lrow<<32 | pk) into epack8 staging.

__global__ __launch_bounds__(512) void sg_k(const int* __restrict__ rows,
                                            const int* __restrict__ cols,
                                            const float* __restrict__ vals,
                                            const u32* __restrict__ G,
                                            u64* __restrict__ epack8,
                                            const float* __restrict__ A,
                                            const bf16* __restrict__ Bt,
                                            const float* __restrict__ bias,
                                            bf16* __restrict__ C) {
    __shared__ __attribute__((aligned(16))) char smem[49152];
    int bid = blockIdx.x, tid = threadIdx.x;
    int wid = tid >> 6, lane = tid & 63;

    if (bid < NCHUNK) {
        // ---- scatter part ----
        u32* cur = (u32*)smem;            // NB
        u32* wt  = (u32*)(smem + 1024);   // 4
        int c = bid;
        u32 tot = 0, pre = 0, incl = 0;
        if (tid < 256) {
            if (tid < NB) {
                for (int cc = 0; cc < NCHUNK; cc++) {
                    u32 v = G[tid * NCHUNK + cc];
                    tot += v;
                    if (cc < c) pre += v;
                }
            }
            incl = tot;
#pragma unroll
            for (int off = 1; off < 64; off <<= 1) {
                u32 u = __shfl_up(incl, off, 64);
                if (lane >= off) incl += u;
            }
            if (lane == 63) wt[wid] = incl;
        }
        __syncthreads();
        if (tid < 256) {
            u32 wpre = 0;
#pragma unroll
            for (int w = 0; w < 4; w++)
                if (w < wid) wpre += wt[w];
            if (tid < NB) cur[tid] = (wpre + incl - tot) + pre;
        }
        __syncthreads();
        int base = c * CHUNK;
        int end = base + CHUNK; if (end > N_EDGES) end = N_EDGES;
        for (int e = base + tid; e < end; e += 512) {
            int r = rows[e];
            unsigned short vb = __builtin_bit_cast(unsigned short, (bf16)vals[e]);
            u32 pk = ((u32)cols[e] << 16) | (u32)vb;
            u32 p = atomicAdd(&cur[r >> 8], 1);
            epack8[p] = ((u64)(u32)(r & 255) << 32) | (u64)pk;
        }
        return;
    }

    // ---- gemm1 part: BM=128, BN=256, BK=64, XOR-swizzled LDS (R14 proven) ----
    constexpr int BM = 128, BK = 64;
    bf16* As = (bf16*)smem;            // 16 KB
    bf16* Bs = (bf16*)(smem + 16384);  // 32 KB
    int wr = wid >> 2, wc = wid & 3;
    int l15 = lane & 15, hi = lane >> 4;
    int sw = l15 & 7;
    int bm = bid - NCHUNK;

    f32x4 acc[4][4];
#pragma unroll
    for (int m = 0; m < 4; m++)
#pragma unroll
        for (int n = 0; n < 4; n++) acc[m][n] = (f32x4){0.f, 0.f, 0.f, 0.f};

    for (int kt = 0; kt < F_IN; kt += BK) {
#pragma unroll
        for (int j = 0; j < 4; j++) {
            int ch = j * 512 + tid;
            int row = ch >> 3, kc = ch & 7;
            int kcs = kc ^ (row & 7);
            gl_lds16(Bt + (size_t)row * F_IN + kt + kcs * 8,
                     &Bs[(j * 512 + wid * 64) * 8]);
        }
#pragma unroll
        for (int j = 0; j < 2; j++) {
            int ch = j * 512 + tid;
            int row = ch >> 3, kc = ch & 7;
            int ar = bm * BM + row;
            if (ar >= N_NODES) ar = N_NODES - 1;
            const f32x4* src = (const f32x4*)(A + (size_t)ar * F_IN + kt + kc * 8);
            f32x4 u = src[0], v = src[1];
            bf16x8 o;
            o[0] = (bf16)u[0]; o[1] = (bf16)u[1]; o[2] = (bf16)u[2]; o[3] = (bf16)u[3];
            o[4] = (bf16)v[0]; o[5] = (bf16)v[1]; o[6] = (bf16)v[2]; o[7] = (bf16)v[3];
            *(bf16x8*)&As[row * BK + (kc ^ (row & 7)) * 8] = o;
        }
        __syncthreads();

        bf16x8 afr[2][4], bfr[2][4];
#pragma unroll
        for (int kk = 0; kk < 2; kk++) {
            int c = (kk * 4 + hi) ^ sw;
#pragma unroll
            for (int m = 0; m < 4; m++)
                afr[kk][m] = *(const bf16x8*)&As[(wr * 64 + m * 16 + l15) * BK + c * 8];
#pragma unroll
            for (int n = 0; n < 4; n++)
                bfr[kk][n] = *(const bf16x8*)&Bs[(wc * 64 + n * 16 + l15) * BK + c * 8];
        }
#pragma unroll
        for (int kk = 0; kk < 2; kk++)
#pragma unroll
            for (int m = 0; m < 4; m++)
#pragma unroll
                for (int n = 0; n < 4; n++)
                    acc[m][n] = __builtin_amdgcn_mfma_f32_16x16x32_bf16(
                        afr[kk][m], bfr[kk][n], acc[m][n], 0, 0, 0);
        __syncthreads();
    }

#pragma unroll
    for (int m = 0; m < 4; m++) {
        int row0 = bm * BM + wr * 64 + m * 16 + hi * 4;
#pragma unroll
        for (int n = 0; n < 4; n++) {
            int col = wc * 64 + n * 16 + l15;
            float bz = bias[col];
#pragma unroll
            for (int r = 0; r < 4; r++) {
                int row = row0 + r;
                if (row < N_NODES)
                    C[(size_t)row * H_DIM + col] = (bf16)(acc[m][n][r] + bz);
            }
        }
    }
}

// ---------------- sortC: in-LDS counting sort within bucket; reads epack8, writes epack ----------------

__global__ __launch_bounds__(256) void sortC_k(const u64* __restrict__ epack8,
                                               u32* __restrict__ epack,
                                               const u32* __restrict__ G,
                                               int* __restrict__ starts) {
    __shared__ u32 edat[BCAP];
    __shared__ u32 sdat[BCAP];
    __shared__ u8  erow[BCAP];
    __shared__ u32 h[4 * 256];
    __shared__ u32 cur[256];
    __shared__ u32 wt1[4], wt2[4];
    __shared__ u32 sh_s, sh_n;
    int b = blockIdx.x, tid = threadIdx.x, wid = tid >> 6, lane = tid & 63;

    u32 btot = 0;
    if (tid < NB)
        for (int cc = 0; cc < NCHUNK; cc++) btot += G[tid * NCHUNK + cc];
    u32 bincl = btot;
#pragma unroll
    for (int off = 1; off < 64; off <<= 1) {
        u32 u = __shfl_up(bincl, off, 64);
        if (lane >= off) bincl += u;
    }
    if (lane == 63) wt1[wid] = bincl;
    __syncthreads();
    u32 bwpre = 0;
#pragma unroll
    for (int w = 0; w < 4; w++)
        if (w < wid) bwpre += wt1[w];
    if (tid == b) { sh_s = bwpre + bincl - btot; sh_n = btot; }
    __syncthreads();
    int s = (int)sh_s;
    int n = (int)sh_n;
    if (n > BCAP) n = BCAP;

    for (int i = tid; i < n; i += 256) {
        u64 v = epack8[s + i];
        edat[i] = (u32)v;
        erow[i] = (u8)(v >> 32);
    }
    for (int i = tid; i < 1024; i += 256) h[i] = 0;
    __syncthreads();
    for (int i = tid; i < n; i += 256) atomicAdd(&h[wid * 256 + erow[i]], 1);
    __syncthreads();
    u32 tot = h[tid] + h[256 + tid] + h[512 + tid] + h[768 + tid];
    u32 incl = tot;
#pragma unroll
    for (int off = 1; off < 64; off <<= 1) {
        u32 u = __shfl_up(incl, off, 64);
        if (lane >= off) incl += u;
    }
    if (lane == 63) wt2[wid] = incl;
    __syncthreads();
    u32 wpre = 0;
#pragma unroll
    for (int w = 0; w < 4; w++)
        if (w < wid) wpre += wt2[w];
    u32 excl = wpre + incl - tot;
    cur[tid] = excl;
    int grow = b * 256 + tid;
    if (grow < N_NODES) starts[grow] = s + (int)excl;
    if (b == 0 && tid == 0) starts[N_NODES] = N_EDGES;
    __syncthreads();
    for (int i = tid; i < n; i += 256) {
        u32 p = atomicAdd(&cur[erow[i]], 1);
        sdat[p] = edat[i];
    }
    __syncthreads();
    for (int i = tid; i < n; i += 256) epack[s + i] = sdat[i];
}

// ---------------- GEMM2: C[M,64] = x16[M,256] @ W2t^T + b2, XOR-swizzled LDS ----------------

__global__ __launch_bounds__(256) void gemm2_k(const bf16* __restrict__ A,
                                               const bf16* __restrict__ Bt,
                                               const float* __restrict__ bias,
                                               bf16* __restrict__ C) {
    constexpr int BM = 128, BK = 64;
    __shared__ bf16 As[BM * BK];
    __shared__ bf16 Bs[64 * BK];

    int tid = threadIdx.x;
    int wid = tid >> 6, lane = tid & 63;
    int wr = wid >> 1, wc = wid & 1;
    int l15 = lane & 15, hi = lane >> 4;
    int sw = l15 & 7;
    int bm = blockIdx.x;

    f32x4 acc[4][2];
#pragma unroll
    for (int m = 0; m < 4; m++)
#pragma unroll
        for (int n = 0; n < 2; n++) acc[m][n] = (f32x4){0.f, 0.f, 0.f, 0.f};

    for (int kt = 0; kt < H_DIM; kt += BK) {
#pragma unroll
        for (int j = 0; j < 4; j++) {
            int ch = j * 256 + tid;
            int row = ch >> 3, kc = ch & 7;
            int kcs = kc ^ (row & 7);
            gl_lds16(A + (size_t)(bm * BM + row) * H_DIM + kt + kcs * 8,
                     &As[(j * 256 + wid * 64) * 8]);
        }
#pragma unroll
        for (int j = 0; j < 2; j++) {
            int ch = j * 256 + tid;
            int row = ch >> 3, kc = ch & 7;
            int kcs = kc ^ (row & 7);
            gl_lds16(Bt + (size_t)row * H_DIM + kt + kcs * 8,
                     &Bs[(j * 256 + wid * 64) * 8]);
        }
        __syncthreads();

        bf16x8 afr[2][4], bfr[2][2];
#pragma unroll
        for (int kk = 0; kk < 2; kk++) {
            int c = (kk * 4 + hi) ^ sw;
#pragma unroll
            for (int m = 0; m < 4; m++)
                afr[kk][m] = *(const bf16x8*)&As[(wr * 64 + m * 16 + l15) * BK + c * 8];
#pragma unroll
            for (int n = 0; n < 2; n++)
                bfr[kk][n] = *(const bf16x8*)&Bs[(wc * 32 + n * 16 + l15) * BK + c * 8];
        }
#pragma unroll
        for (int kk = 0; kk < 2; kk++)
#pragma unroll
            for (int m = 0; m < 4; m++)
#pragma unroll
                for (int n = 0; n < 2; n++)
                    acc[m][n] = __builtin_amdgcn_mfma_f32_16x16x32_bf16(
                        afr[kk][m], bfr[kk][n], acc[m][n], 0, 0, 0);
        __syncthreads();
    }

#pragma unroll
    for (int m = 0; m < 4; m++) {
        int row0 = bm * BM + wr * 64 + m * 16 + hi * 4;
#pragma unroll
        for (int n = 0; n < 2; n++) {
            int col = wc * 32 + n * 16 + l15;
            float bz = bias[col];
#pragma unroll
            for (int r = 0; r < 4; r++) {
                int row = row0 + r;
                if (row < N_NODES)
                    C[(size_t)row * C_DIM + col] = (bf16)(acc[m][n][r] + bz);
            }
        }
    }
}

// ---------------- SpMM1: row-per-wave, 8 gathers in flight, NT streams ----------------
// Parked at line-BW roofline: 800K edges x 8 lines = 410 MB @ ~6.6 TB/s ~ 62 us.

__global__ __launch_bounds__(256) void spmm1_k(const int* __restrict__ starts,
                                               const u32* __restrict__ epack,
                                               const bf16* __restrict__ s1,
                                               bf16* __restrict__ x16) {
    int wid = threadIdx.x >> 6, lane = threadIdx.x & 63;
    int row = blockIdx.x * 4 + wid;
    if (row >= N_NODES) return;
    int s = starts[row], e = starts[row + 1];
    f32x4 acc = (f32x4){0.f, 0.f, 0.f, 0.f};
    const bf16* s1l = s1 + lane * 4;
    int p = s;
    for (; p + 8 <= e; p += 8) {
        u32 k0 = __builtin_nontemporal_load(epack + p);
        u32 k1 = __builtin_nontemporal_load(epack + p + 1);
        u32 k2 = __builtin_nontemporal_load(epack + p + 2);
        u32 k3 = __builtin_nontemporal_load(epack + p + 3);
        u32 k4 = __builtin_nontemporal_load(epack + p + 4);
        u32 k5 = __builtin_nontemporal_load(epack + p + 5);
        u32 k6 = __builtin_nontemporal_load(epack + p + 6);
        u32 k7 = __builtin_nontemporal_load(epack + p + 7);
        bf16x4 g0 = *(const bf16x4*)(s1l + (size_t)(k0 >> 16) * H_DIM);
        bf16x4 g1 = *(const bf16x4*)(s1l + (size_t)(k1 >> 16) * H_DIM);
        bf16x4 g2 = *(const bf16x4*)(s1l + (size_t)(k2 >> 16) * H_DIM);
        bf16x4 g3 = *(const bf16x4*)(s1l + (size_t)(k3 >> 16) * H_DIM);
        bf16x4 g4 = *(const bf16x4*)(s1l + (size_t)(k4 >> 16) * H_DIM);
        bf16x4 g5 = *(const bf16x4*)(s1l + (size_t)(k5 >> 16) * H_DIM);
        bf16x4 g6 = *(const bf16x4*)(s1l + (size_t)(k6 >> 16) * H_DIM);
        bf16x4 g7 = *(const bf16x4*)(s1l + (size_t)(k7 >> 16) * H_DIM);
        float v0 = unpack_val(k0), v1 = unpack_val(k1), v2 = unpack_val(k2), v3 = unpack_val(k3);
        float v4 = unpack_val(k4), v5 = unpack_val(k5), v6 = unpack_val(k6), v7 = unpack_val(k7);
#pragma unroll
        for (int j = 0; j < 4; j++)
            acc[j] += v0 * (float)g0[j] + v1 * (float)g1[j] +
                      v2 * (float)g2[j] + v3 * (float)g3[j] +
                      v4 * (float)g4[j] + v5 * (float)g5[j] +
                      v6 * (float)g6[j] + v7 * (float)g7[j];
    }
    for (; p < e; ++p) {
        u32 k = __builtin_nontemporal_load(epack + p);
        float v = unpack_val(k);
        bf16x4 g = *(const bf16x4*)(s1l + (size_t)(k >> 16) * H_DIM);
#pragma unroll
        for (int j = 0; j < 4; j++) acc[j] += v * (float)g[j];
    }
    bf16x4 o;
#pragma unroll
    for (int j = 0; j < 4; j++) o[j] = (bf16)fmaxf(acc[j], 0.f);
    u64 bits = __builtin_bit_cast(u64, o);
    __builtin_nontemporal_store(bits, (u64*)(x16 + (size_t)row * H_DIM + lane * 4));
}

// ---------------- SpMM2 + log_softmax fused: D=64, lane = class, 8-wide, NT ----------------

__global__ __launch_bounds__(256) void spmm2_sm_k(const int* __restrict__ starts,
                                                  const u32* __restrict__ epack,
                                                  const bf16* __restrict__ s2,
                                                  float* __restrict__ out) {
    int wid = threadIdx.x >> 6, lane = threadIdx.x & 63;
    int row = blockIdx.x * 4 + wid;
    if (row >= N_NODES) return;
    int s = starts[row], e = starts[row + 1];
    float acc = 0.f;
    int p = s;
    for (; p + 8 <= e; p += 8) {
        u32 k0 = __builtin_nontemporal_load(epack + p);
        u32 k1 = __builtin_nontemporal_load(epack + p + 1);
        u32 k2 = __builtin_nontemporal_load(epack + p + 2);
        u32 k3 = __builtin_nontemporal_load(epack + p + 3);
        u32 k4 = __builtin_nontemporal_load(epack + p + 4);
        u32 k5 = __builtin_nontemporal_load(epack + p + 5);
        u32 k6 = __builtin_nontemporal_load(epack + p + 6);
        u32 k7 = __builtin_nontemporal_load(epack + p + 7);
        float g0 = (float)s2[(size_t)(k0 >> 16) * C_DIM + lane];
        float g1 = (float)s2[(size_t)(k1 >> 16) * C_DIM + lane];
        float g2 = (float)s2[(size_t)(k2 >> 16) * C_DIM + lane];
        float g3 = (float)s2[(size_t)(k3 >> 16) * C_DIM + lane];
        float g4 = (float)s2[(size_t)(k4 >> 16) * C_DIM + lane];
        float g5 = (float)s2[(size_t)(k5 >> 16) * C_DIM + lane];
        float g6 = (float)s2[(size_t)(k6 >> 16) * C_DIM + lane];
        float g7 = (float)s2[(size_t)(k7 >> 16) * C_DIM + lane];
        acc += unpack_val(k0) * g0 + unpack_val(k1) * g1 +
               unpack_val(k2) * g2 + unpack_val(k3) * g3 +
               unpack_val(k4) * g4 + unpack_val(k5) * g5 +
               unpack_val(k6) * g6 + unpack_val(k7) * g7;
    }
    for (; p < e; ++p) {
        u32 k = __builtin_nontemporal_load(epack + p);
        acc += unpack_val(k) * (float)s2[(size_t)(k >> 16) * C_DIM + lane];
    }
    float mx = acc;
#pragma unroll
    for (int off = 32; off >= 1; off >>= 1) mx = fmaxf(mx, __shfl_xor(mx, off, 64));
    float ex = expf(acc - mx);
    float se = ex;
#pragma unroll
    for (int off = 32; off >= 1; off >>= 1) se += __shfl_xor(se, off, 64);
    __builtin_nontemporal_store((acc - mx) - logf(se),
                                out + (size_t)row * C_DIM + lane);
}

// ---------------- launch ----------------

extern "C" void kernel_launch(void* const* d_in, const int* in_sizes, int n_in,
                              void* d_out, int out_size, void* d_ws, size_t ws_size,
                              hipStream_t stream) {
    const float* nf   = (const float*)d_in[0];
    const int*   rows = (const int*)d_in[1];
    const int*   cols = (const int*)d_in[2];
    const float* vals = (const float*)d_in[3];
    const float* W1   = (const float*)d_in[4];
    const float* b1   = (const float*)d_in[5];
    const float* W2   = (const float*)d_in[6];
    const float* b2   = (const float*)d_in[7];
    float* out = (float*)d_out;

    char* w = (char*)d_ws;
    auto alloc = [&](size_t b) { void* p = (void*)w; w += (b + 255) & ~(size_t)255; return p; };

    bf16* x16  = (bf16*)alloc((size_t)MPAD * H_DIM * 2);
    bf16* sup1 = (bf16*)alloc((size_t)N_NODES * H_DIM * 2);
    bf16* sup2 = sup1;   // aliases sup1 (dead by then)
    bf16* W1t = (bf16*)alloc((size_t)H_DIM * F_IN * 2);
    bf16* W2t = (bf16*)alloc((size_t)C_DIM * H_DIM * 2);
    int* starts = (int*)alloc((size_t)(N_NODES + 1) * 4);
    u32* G      = (u32*)alloc((size_t)NB * NCHUNK * 4);
    u32* epack  = (u32*)alloc((size_t)N_EDGES * 4);
    u64* epack8 = (u64*)alloc((size_t)N_EDGES * 8);

    // 1) hist + weight transpose (independent, fused)
    prep_k<<<NCHUNK + 144, 1024, 0, stream>>>(rows, W1, W2, G, W1t, W2t);
    // 2) scatter (196 blocks, single u64 store/edge) + layer-1 GEMM (391 blocks)
    sg_k<<<NCHUNK + MPAD / 128, 512, 0, stream>>>(rows, cols, vals, G, epack8,
                                                  nf, W1t, b1, sup1);
    // 3) in-bucket sort (epack8 -> sorted u32 epack)
    sortC_k<<<NB, 256, 0, stream>>>(epack8, epack, G, starts);
    // 4) aggregate layer 1
    spmm1_k<<<(N_NODES + 3) / 4, 256, 0, stream>>>(starts, epack, sup1, x16);
    // 5) layer 2 GEMM (swizzled LDS)
    gemm2_k<<<MPAD / 128, 256, 0, stream>>>(x16, W2t, b2, sup2);
    // 6) aggregate layer 2 + log_softmax
    spmm2_sm_k<<<(N_NODES + 3) / 4, 256, 0, stream>>>(starts, epack, sup2, out);

    (void)in_sizes; (void)n_in; (void)out_size; (void)ws_size;
}

// Round 18
// 168.075 us; speedup vs baseline: 1.0918x; 1.0301x over previous
//
#include <hip/hip_runtime.h>

#define N_NODES 50000
#define N_EDGES 800000
#define F_IN    512
#define H_DIM   256
#define C_DIM   64
#define MPAD    50048   // 782 * 64

// sort geometry: bucket = row >> 8 (256 rows/bucket), chunk = 4096 edges
#define NB      196
#define NCHUNK  196     // ceil(800000/4096)
#define CHUNK   4096
#define BCAP    6144

typedef __bf16 bf16;
typedef __bf16 bf16x4 __attribute__((ext_vector_type(4)));
typedef __bf16 bf16x8 __attribute__((ext_vector_type(8)));
typedef float  f32x4  __attribute__((ext_vector_type(4)));
typedef unsigned int u32;
typedef unsigned long long u64;
typedef unsigned char u8;

__device__ __forceinline__ void gl_lds16(const void* g, void* l) {
    __builtin_amdgcn_global_load_lds(
        (const __attribute__((address_space(1))) u32*)g,
        (__attribute__((address_space(3))) u32*)l, 16, 0, 0);
}

__device__ __forceinline__ float unpack_val(u32 pk) {
    return __builtin_bit_cast(float, pk << 16);
}

// ---------------- prep: edge histogram (blocks 0..NCHUNK-1) + weight transpose ----------------

__global__ __launch_bounds__(1024) void prep_k(const int* __restrict__ rows,
                                               const float* __restrict__ W1,
                                               const float* __restrict__ W2,
                                               u32* __restrict__ G,
                                               bf16* __restrict__ W1t,
                                               bf16* __restrict__ W2t) {
    __shared__ u32 h[16 * NB];
    int bid = blockIdx.x, tid = threadIdx.x;
    if (bid < NCHUNK) {
        int wid = tid >> 6;
        for (int i = tid; i < 16 * NB; i += 1024) h[i] = 0;
        __syncthreads();
        int base = bid * CHUNK;
        int end = base + CHUNK; if (end > N_EDGES) end = N_EDGES;
        for (int e = base + tid; e < end; e += 1024)
            atomicAdd(&h[wid * NB + (rows[e] >> 8)], 1);
        __syncthreads();
        if (tid < NB) {
            u32 s = 0;
#pragma unroll
            for (int w = 0; w < 16; w++) s += h[w * NB + tid];
            G[tid * NCHUNK + bid] = s;
        }
    } else {
        int i = (bid - NCHUNK) * 1024 + tid;   // 144 blocks cover 147456 elems
        if (i < F_IN * H_DIM) {
            int k = i >> 8, n = i & 255;
            W1t[n * F_IN + k] = (bf16)W1[i];
        } else {
            int j = i - F_IN * H_DIM;
            if (j < H_DIM * C_DIM) {
                int k = j >> 6, n = j & 63;
                W2t[n * H_DIM + k] = (bf16)W2[j];
            }
        }
    }
}

// ---------------- merged: scatterB (blocks 0..NCHUNK-1) + GEMM1 (blocks NCHUNK..) ----------------
// GEMM1: BM=64, BN=256, BK=64, 512 threads (8 waves x 64x32 slice), 40KB LDS -> 4 blocks/CU.

__global__ __launch_bounds__(512) void sg_k(const int* __restrict__ rows,
                                            const int* __restrict__ cols,
                                            const float* __restrict__ vals,
                                            const u32* __restrict__ G,
                                            u64* __restrict__ epack8,
                                            const float* __restrict__ A,
                                            const bf16* __restrict__ Bt,
                                            const float* __restrict__ bias,
                                            bf16* __restrict__ C) {
    __shared__ __attribute__((aligned(16))) char smem[40960];
    int bid = blockIdx.x, tid = threadIdx.x;
    int wid = tid >> 6, lane = tid & 63;

    if (bid < NCHUNK) {
        // ---- scatter part: single u64 store per edge ----
        u32* cur = (u32*)smem;            // NB
        u32* wt  = (u32*)(smem + 1024);   // 4
        int c = bid;
        u32 tot = 0, pre = 0, incl = 0;
        if (tid < 256) {
            if (tid < NB) {
                for (int cc = 0; cc < NCHUNK; cc++) {
                    u32 v = G[tid * NCHUNK + cc];
                    tot += v;
                    if (cc < c) pre += v;
                }
            }
            incl = tot;
#pragma unroll
            for (int off = 1; off < 64; off <<= 1) {
                u32 u = __shfl_up(incl, off, 64);
                if (lane >= off) incl += u;
            }
            if (lane == 63) wt[wid] = incl;
        }
        __syncthreads();
        if (tid < 256) {
            u32 wpre = 0;
#pragma unroll
            for (int w = 0; w < 4; w++)
                if (w < wid) wpre += wt[w];
            if (tid < NB) cur[tid] = (wpre + incl - tot) + pre;
        }
        __syncthreads();
        int base = c * CHUNK;
        int end = base + CHUNK; if (end > N_EDGES) end = N_EDGES;
        for (int e = base + tid; e < end; e += 512) {
            int r = rows[e];
            unsigned short vb = __builtin_bit_cast(unsigned short, (bf16)vals[e]);
            u32 pk = ((u32)cols[e] << 16) | (u32)vb;
            u32 p = atomicAdd(&cur[r >> 8], 1);
            epack8[p] = ((u64)(u32)(r & 255) << 32) | (u64)pk;
        }
        return;
    }

    // ---- gemm1 part: BM=64, BN=256, BK=64, XOR-swizzled LDS ----
    constexpr int BM = 64, BK = 64;
    bf16* As = (bf16*)smem;            //  8 KB
    bf16* Bs = (bf16*)(smem + 8192);   // 32 KB
    int l15 = lane & 15, hi = lane >> 4;
    int sw = l15 & 7;
    int bm = bid - NCHUNK;

    f32x4 acc[4][2];
#pragma unroll
    for (int m = 0; m < 4; m++)
#pragma unroll
        for (int n = 0; n < 2; n++) acc[m][n] = (f32x4){0.f, 0.f, 0.f, 0.f};

    for (int kt = 0; kt < F_IN; kt += BK) {
        // B tile: 256x64 bf16 = 32 KB; 4 gl_lds per thread, source pre-swizzled
#pragma unroll
        for (int j = 0; j < 4; j++) {
            int ch = j * 512 + tid;
            int row = ch >> 3, kc = ch & 7;
            int kcs = kc ^ (row & 7);
            gl_lds16(Bt + (size_t)row * F_IN + kt + kcs * 8,
                     &Bs[(j * 512 + wid * 64) * 8]);
        }
        // A tile: 64x64 f32 = 16 KB; 1 chunk (32B) per thread, reg-staged -> bf16 swizzled
        {
            int row = tid >> 3, kc = tid & 7;
            int ar = bm * BM + row;
            if (ar >= N_NODES) ar = N_NODES - 1;
            const f32x4* src = (const f32x4*)(A + (size_t)ar * F_IN + kt + kc * 8);
            f32x4 u = src[0], v = src[1];
            bf16x8 o;
            o[0] = (bf16)u[0]; o[1] = (bf16)u[1]; o[2] = (bf16)u[2]; o[3] = (bf16)u[3];
            o[4] = (bf16)v[0]; o[5] = (bf16)v[1]; o[6] = (bf16)v[2]; o[7] = (bf16)v[3];
            *(bf16x8*)&As[row * BK + (kc ^ (row & 7)) * 8] = o;
        }
        __syncthreads();

        bf16x8 afr[2][4], bfr[2][2];
#pragma unroll
        for (int kk = 0; kk < 2; kk++) {
            int c = (kk * 4 + hi) ^ sw;
#pragma unroll
            for (int m = 0; m < 4; m++)
                afr[kk][m] = *(const bf16x8*)&As[(m * 16 + l15) * BK + c * 8];
#pragma unroll
            for (int n = 0; n < 2; n++)
                bfr[kk][n] = *(const bf16x8*)&Bs[(wid * 32 + n * 16 + l15) * BK + c * 8];
        }
#pragma unroll
        for (int kk = 0; kk < 2; kk++)
#pragma unroll
            for (int m = 0; m < 4; m++)
#pragma unroll
                for (int n = 0; n < 2; n++)
                    acc[m][n] = __builtin_amdgcn_mfma_f32_16x16x32_bf16(
                        afr[kk][m], bfr[kk][n], acc[m][n], 0, 0, 0);
        __syncthreads();
    }

#pragma unroll
    for (int m = 0; m < 4; m++) {
        int row0 = bm * BM + m * 16 + hi * 4;
#pragma unroll
        for (int n = 0; n < 2; n++) {
            int col = wid * 32 + n * 16 + l15;
            float bz = bias[col];
#pragma unroll
            for (int r = 0; r < 4; r++) {
                int row = row0 + r;
                if (row < N_NODES)
                    C[(size_t)row * H_DIM + col] = (bf16)(acc[m][n][r] + bz);
            }
        }
    }
}

// ---------------- sortC: in-LDS counting sort within bucket; reads epack8, writes epack ----------------

__global__ __launch_bounds__(256) void sortC_k(const u64* __restrict__ epack8,
                                               u32* __restrict__ epack,
                                               const u32* __restrict__ G,
                                               int* __restrict__ starts) {
    __shared__ u32 edat[BCAP];
    __shared__ u32 sdat[BCAP];
    __shared__ u8  erow[BCAP];
    __shared__ u32 h[4 * 256];
    __shared__ u32 cur[256];
    __shared__ u32 wt1[4], wt2[4];
    __shared__ u32 sh_s, sh_n;
    int b = blockIdx.x, tid = threadIdx.x, wid = tid >> 6, lane = tid & 63;

    u32 btot = 0;
    if (tid < NB)
        for (int cc = 0; cc < NCHUNK; cc++) btot += G[tid * NCHUNK + cc];
    u32 bincl = btot;
#pragma unroll
    for (int off = 1; off < 64; off <<= 1) {
        u32 u = __shfl_up(bincl, off, 64);
        if (lane >= off) bincl += u;
    }
    if (lane == 63) wt1[wid] = bincl;
    __syncthreads();
    u32 bwpre = 0;
#pragma unroll
    for (int w = 0; w < 4; w++)
        if (w < wid) bwpre += wt1[w];
    if (tid == b) { sh_s = bwpre + bincl - btot; sh_n = btot; }
    __syncthreads();
    int s = (int)sh_s;
    int n = (int)sh_n;
    if (n > BCAP) n = BCAP;

    for (int i = tid; i < n; i += 256) {
        u64 v = epack8[s + i];
        edat[i] = (u32)v;
        erow[i] = (u8)(v >> 32);
    }
    for (int i = tid; i < 1024; i += 256) h[i] = 0;
    __syncthreads();
    for (int i = tid; i < n; i += 256) atomicAdd(&h[wid * 256 + erow[i]], 1);
    __syncthreads();
    u32 tot = h[tid] + h[256 + tid] + h[512 + tid] + h[768 + tid];
    u32 incl = tot;
#pragma unroll
    for (int off = 1; off < 64; off <<= 1) {
        u32 u = __shfl_up(incl, off, 64);
        if (lane >= off) incl += u;
    }
    if (lane == 63) wt2[wid] = incl;
    __syncthreads();
    u32 wpre = 0;
#pragma unroll
    for (int w = 0; w < 4; w++)
        if (w < wid) wpre += wt2[w];
    u32 excl = wpre + incl - tot;
    cur[tid] = excl;
    int grow = b * 256 + tid;
    if (grow < N_NODES) starts[grow] = s + (int)excl;
    if (b == 0 && tid == 0) starts[N_NODES] = N_EDGES;
    __syncthreads();
    for (int i = tid; i < n; i += 256) {
        u32 p = atomicAdd(&cur[erow[i]], 1);
        sdat[p] = edat[i];
    }
    __syncthreads();
    for (int i = tid; i < n; i += 256) epack[s + i] = sdat[i];
}

// ---------------- GEMM2: C[M,64] = x16[M,256] @ W2t^T + b2, XOR-swizzled LDS ----------------

__global__ __launch_bounds__(256) void gemm2_k(const bf16* __restrict__ A,
                                               const bf16* __restrict__ Bt,
                                               const float* __restrict__ bias,
                                               bf16* __restrict__ C) {
    constexpr int BM = 128, BK = 64;
    __shared__ bf16 As[BM * BK];
    __shared__ bf16 Bs[64 * BK];

    int tid = threadIdx.x;
    int wid = tid >> 6, lane = tid & 63;
    int wr = wid >> 1, wc = wid & 1;
    int l15 = lane & 15, hi = lane >> 4;
    int sw = l15 & 7;
    int bm = blockIdx.x;

    f32x4 acc[4][2];
#pragma unroll
    for (int m = 0; m < 4; m++)
#pragma unroll
        for (int n = 0; n < 2; n++) acc[m][n] = (f32x4){0.f, 0.f, 0.f, 0.f};

    for (int kt = 0; kt < H_DIM; kt += BK) {
#pragma unroll
        for (int j = 0; j < 4; j++) {
            int ch = j * 256 + tid;
            int row = ch >> 3, kc = ch & 7;
            int kcs = kc ^ (row & 7);
            gl_lds16(A + (size_t)(bm * BM + row) * H_DIM + kt + kcs * 8,
                     &As[(j * 256 + wid * 64) * 8]);
        }
#pragma unroll
        for (int j = 0; j < 2; j++) {
            int ch = j * 256 + tid;
            int row = ch >> 3, kc = ch & 7;
            int kcs = kc ^ (row & 7);
            gl_lds16(Bt + (size_t)row * H_DIM + kt + kcs * 8,
                     &Bs[(j * 256 + wid * 64) * 8]);
        }
        __syncthreads();

        bf16x8 afr[2][4], bfr[2][2];
#pragma unroll
        for (int kk = 0; kk < 2; kk++) {
            int c = (kk * 4 + hi) ^ sw;
#pragma unroll
            for (int m = 0; m < 4; m++)
                afr[kk][m] = *(const bf16x8*)&As[(wr * 64 + m * 16 + l15) * BK + c * 8];
#pragma unroll
            for (int n = 0; n < 2; n++)
                bfr[kk][n] = *(const bf16x8*)&Bs[(wc * 32 + n * 16 + l15) * BK + c * 8];
        }
#pragma unroll
        for (int kk = 0; kk < 2; kk++)
#pragma unroll
            for (int m = 0; m < 4; m++)
#pragma unroll
                for (int n = 0; n < 2; n++)
                    acc[m][n] = __builtin_amdgcn_mfma_f32_16x16x32_bf16(
                        afr[kk][m], bfr[kk][n], acc[m][n], 0, 0, 0);
        __syncthreads();
    }

#pragma unroll
    for (int m = 0; m < 4; m++) {
        int row0 = bm * BM + wr * 64 + m * 16 + hi * 4;
#pragma unroll
        for (int n = 0; n < 2; n++) {
            int col = wc * 32 + n * 16 + l15;
            float bz = bias[col];
#pragma unroll
            for (int r = 0; r < 4; r++) {
                int row = row0 + r;
                if (row < N_NODES)
                    C[(size_t)row * C_DIM + col] = (bf16)(acc[m][n][r] + bz);
            }
        }
    }
}

// ---------------- SpMM1: row-per-wave, 8 gathers in flight, NT streams ----------------
// Parked at line-BW roofline: 800K edges x 8 lines = 410 MB @ ~6.6 TB/s ~ 62 us.

__global__ __launch_bounds__(256) void spmm1_k(const int* __restrict__ starts,
                                               const u32* __restrict__ epack,
                                               const bf16* __restrict__ s1,
                                               bf16* __restrict__ x16) {
    int wid = threadIdx.x >> 6, lane = threadIdx.x & 63;
    int row = blockIdx.x * 4 + wid;
    if (row >= N_NODES) return;
    int s = starts[row], e = starts[row + 1];
    f32x4 acc = (f32x4){0.f, 0.f, 0.f, 0.f};
    const bf16* s1l = s1 + lane * 4;
    int p = s;
    for (; p + 8 <= e; p += 8) {
        u32 k0 = __builtin_nontemporal_load(epack + p);
        u32 k1 = __builtin_nontemporal_load(epack + p + 1);
        u32 k2 = __builtin_nontemporal_load(epack + p + 2);
        u32 k3 = __builtin_nontemporal_load(epack + p + 3);
        u32 k4 = __builtin_nontemporal_load(epack + p + 4);
        u32 k5 = __builtin_nontemporal_load(epack + p + 5);
        u32 k6 = __builtin_nontemporal_load(epack + p + 6);
        u32 k7 = __builtin_nontemporal_load(epack + p + 7);
        bf16x4 g0 = *(const bf16x4*)(s1l + (size_t)(k0 >> 16) * H_DIM);
        bf16x4 g1 = *(const bf16x4*)(s1l + (size_t)(k1 >> 16) * H_DIM);
        bf16x4 g2 = *(const bf16x4*)(s1l + (size_t)(k2 >> 16) * H_DIM);
        bf16x4 g3 = *(const bf16x4*)(s1l + (size_t)(k3 >> 16) * H_DIM);
        bf16x4 g4 = *(const bf16x4*)(s1l + (size_t)(k4 >> 16) * H_DIM);
        bf16x4 g5 = *(const bf16x4*)(s1l + (size_t)(k5 >> 16) * H_DIM);
        bf16x4 g6 = *(const bf16x4*)(s1l + (size_t)(k6 >> 16) * H_DIM);
        bf16x4 g7 = *(const bf16x4*)(s1l + (size_t)(k7 >> 16) * H_DIM);
        float v0 = unpack_val(k0), v1 = unpack_val(k1), v2 = unpack_val(k2), v3 = unpack_val(k3);
        float v4 = unpack_val(k4), v5 = unpack_val(k5), v6 = unpack_val(k6), v7 = unpack_val(k7);
#pragma unroll
        for (int j = 0; j < 4; j++)
            acc[j] += v0 * (float)g0[j] + v1 * (float)g1[j] +
                      v2 * (float)g2[j] + v3 * (float)g3[j] +
                      v4 * (float)g4[j] + v5 * (float)g5[j] +
                      v6 * (float)g6[j] + v7 * (float)g7[j];
    }
    for (; p < e; ++p) {
        u32 k = __builtin_nontemporal_load(epack + p);
        float v = unpack_val(k);
        bf16x4 g = *(const bf16x4*)(s1l + (size_t)(k >> 16) * H_DIM);
#pragma unroll
        for (int j = 0; j < 4; j++) acc[j] += v * (float)g[j];
    }
    bf16x4 o;
#pragma unroll
    for (int j = 0; j < 4; j++) o[j] = (bf16)fmaxf(acc[j], 0.f);
    u64 bits = __builtin_bit_cast(u64, o);
    __builtin_nontemporal_store(bits, (u64*)(x16 + (size_t)row * H_DIM + lane * 4));
}

// ---------------- SpMM2 + log_softmax fused: D=64, lane = class, 8-wide, NT ----------------

__global__ __launch_bounds__(256) void spmm2_sm_k(const int* __restrict__ starts,
                                                  const u32* __restrict__ epack,
                                                  const bf16* __restrict__ s2,
                                                  float* __restrict__ out) {
    int wid = threadIdx.x >> 6, lane = threadIdx.x & 63;
    int row = blockIdx.x * 4 + wid;
    if (row >= N_NODES) return;
    int s = starts[row], e = starts[row + 1];
    float acc = 0.f;
    int p = s;
    for (; p + 8 <= e; p += 8) {
        u32 k0 = __builtin_nontemporal_load(epack + p);
        u32 k1 = __builtin_nontemporal_load(epack + p + 1);
        u32 k2 = __builtin_nontemporal_load(epack + p + 2);
        u32 k3 = __builtin_nontemporal_load(epack + p + 3);
        u32 k4 = __builtin_nontemporal_load(epack + p + 4);
        u32 k5 = __builtin_nontemporal_load(epack + p + 5);
        u32 k6 = __builtin_nontemporal_load(epack + p + 6);
        u32 k7 = __builtin_nontemporal_load(epack + p + 7);
        float g0 = (float)s2[(size_t)(k0 >> 16) * C_DIM + lane];
        float g1 = (float)s2[(size_t)(k1 >> 16) * C_DIM + lane];
        float g2 = (float)s2[(size_t)(k2 >> 16) * C_DIM + lane];
        float g3 = (float)s2[(size_t)(k3 >> 16) * C_DIM + lane];
        float g4 = (float)s2[(size_t)(k4 >> 16) * C_DIM + lane];
        float g5 = (float)s2[(size_t)(k5 >> 16) * C_DIM + lane];
        float g6 = (float)s2[(size_t)(k6 >> 16) * C_DIM + lane];
        float g7 = (float)s2[(size_t)(k7 >> 16) * C_DIM + lane];
        acc += unpack_val(k0) * g0 + unpack_val(k1) * g1 +
               unpack_val(k2) * g2 + unpack_val(k3) * g3 +
               unpack_val(k4) * g4 + unpack_val(k5) * g5 +
               unpack_val(k6) * g6 + unpack_val(k7) * g7;
    }
    for (; p < e; ++p) {
        u32 k = __builtin_nontemporal_load(epack + p);
        acc += unpack_val(k) * (float)s2[(size_t)(k >> 16) * C_DIM + lane];
    }
    float mx = acc;
#pragma unroll
    for (int off = 32; off >= 1; off >>= 1) mx = fmaxf(mx, __shfl_xor(mx, off, 64));
    float ex = expf(acc - mx);
    float se = ex;
#pragma unroll
    for (int off = 32; off >= 1; off >>= 1) se += __shfl_xor(se, off, 64);
    __builtin_nontemporal_store((acc - mx) - logf(se),
                                out + (size_t)row * C_DIM + lane);
}

// ---------------- launch ----------------

extern "C" void kernel_launch(void* const* d_in, const int* in_sizes, int n_in,
                              void* d_out, int out_size, void* d_ws, size_t ws_size,
                              hipStream_t stream) {
    const float* nf   = (const float*)d_in[0];
    const int*   rows = (const int*)d_in[1];
    const int*   cols = (const int*)d_in[2];
    const float* vals = (const float*)d_in[3];
    const float* W1   = (const float*)d_in[4];
    const float* b1   = (const float*)d_in[5];
    const float* W2   = (const float*)d_in[6];
    const float* b2   = (const float*)d_in[7];
    float* out = (float*)d_out;

    char* w = (char*)d_ws;
    auto alloc = [&](size_t b) { void* p = (void*)w; w += (b + 255) & ~(size_t)255; return p; };

    bf16* x16  = (bf16*)alloc((size_t)MPAD * H_DIM * 2);
    bf16* sup1 = (bf16*)alloc((size_t)N_NODES * H_DIM * 2);
    bf16* sup2 = sup1;   // aliases sup1 (dead by then)
    bf16* W1t = (bf16*)alloc((size_t)H_DIM * F_IN * 2);
    bf16* W2t = (bf16*)alloc((size_t)C_DIM * H_DIM * 2);
    int* starts = (int*)alloc((size_t)(N_NODES + 1) * 4);
    u32* G      = (u32*)alloc((size_t)NB * NCHUNK * 4);
    u32* epack  = (u32*)alloc((size_t)N_EDGES * 4);
    u64* epack8 = (u64*)alloc((size_t)N_EDGES * 8);

    // 1) hist + weight transpose (independent, fused)
    prep_k<<<NCHUNK + 144, 1024, 0, stream>>>(rows, W1, W2, G, W1t, W2t);
    // 2) scatter (196 blocks) + layer-1 GEMM (782 blocks, BM=64, 4 blocks/CU)
    sg_k<<<NCHUNK + MPAD / 64, 512, 0, stream>>>(rows, cols, vals, G, epack8,
                                                 nf, W1t, b1, sup1);
    // 3) in-bucket sort (epack8 -> sorted u32 epack)
    sortC_k<<<NB, 256, 0, stream>>>(epack8, epack, G, starts);
    // 4) aggregate layer 1
    spmm1_k<<<(N_NODES + 3) / 4, 256, 0, stream>>>(starts, epack, sup1, x16);
    // 5) layer 2 GEMM (swizzled LDS)
    gemm2_k<<<MPAD / 128, 256, 0, stream>>>(x16, W2t, b2, sup2);
    // 6) aggregate layer 2 + log_softmax
    spmm2_sm_k<<<(N_NODES + 3) / 4, 256, 0, stream>>>(starts, epack, sup2, out);

    (void)in_sizes; (void)n_in; (void)out_size; (void)ws_size;
}

// Round 19
// 166.240 us; speedup vs baseline: 1.1038x; 1.0110x over previous
//
#include <hip/hip_runtime.h>

#define N_NODES 50000
#define N_EDGES 800000
#define F_IN    512
#define H_DIM   256
#define C_DIM   64
#define MPAD    50048   // 782 * 64

// sort geometry: bucket = row >> 8 (256 rows/bucket), chunk = 4096 edges
#define NB      196
#define NCHUNK  196     // ceil(800000/4096)
#define CHUNK   4096
#define BCAP    6144

typedef __bf16 bf16;
typedef __bf16 bf16x4 __attribute__((ext_vector_type(4)));
typedef __bf16 bf16x8 __attribute__((ext_vector_type(8)));
typedef float  f32x4  __attribute__((ext_vector_type(4)));
typedef unsigned int u32;
typedef unsigned long long u64;
typedef unsigned char u8;

__device__ __forceinline__ void gl_lds16(const void* g, void* l) {
    __builtin_amdgcn_global_load_lds(
        (const __attribute__((address_space(1))) u32*)g,
        (__attribute__((address_space(3))) u32*)l, 16, 0, 0);
}

__device__ __forceinline__ float unpack_val(u32 pk) {
    return __builtin_bit_cast(float, pk << 16);
}

// ---------------- prep: edge histogram (blocks 0..NCHUNK-1) + weight transpose ----------------

__global__ __launch_bounds__(1024) void prep_k(const int* __restrict__ rows,
                                               const float* __restrict__ W1,
                                               const float* __restrict__ W2,
                                               u32* __restrict__ G,
                                               bf16* __restrict__ W1t,
                                               bf16* __restrict__ W2t) {
    __shared__ u32 h[16 * NB];
    int bid = blockIdx.x, tid = threadIdx.x;
    if (bid < NCHUNK) {
        int wid = tid >> 6;
        for (int i = tid; i < 16 * NB; i += 1024) h[i] = 0;
        __syncthreads();
        int base = bid * CHUNK;
        int end = base + CHUNK; if (end > N_EDGES) end = N_EDGES;
        for (int e = base + tid; e < end; e += 1024)
            atomicAdd(&h[wid * NB + (rows[e] >> 8)], 1);
        __syncthreads();
        if (tid < NB) {
            u32 s = 0;
#pragma unroll
            for (int w = 0; w < 16; w++) s += h[w * NB + tid];
            G[tid * NCHUNK + bid] = s;
        }
    } else {
        int i = (bid - NCHUNK) * 1024 + tid;   // 144 blocks cover 147456 elems
        if (i < F_IN * H_DIM) {
            int k = i >> 8, n = i & 255;
            W1t[n * F_IN + k] = (bf16)W1[i];
        } else {
            int j = i - F_IN * H_DIM;
            if (j < H_DIM * C_DIM) {
                int k = j >> 6, n = j & 63;
                W2t[n * H_DIM + k] = (bf16)W2[j];
            }
        }
    }
}

// ---------------- merged: scatterB (blocks 0..NCHUNK-1) + GEMM1 (blocks NCHUNK..) ----------------
// Scatter: LDS bucket-grouping, COALESCED write-out (runs of ~21 edges).
// GEMM1: BM=64, BN=256, BK=64, 512 threads, 40KB LDS -> 4 blocks/CU.

__global__ __launch_bounds__(512) void sg_k(const int* __restrict__ rows,
                                            const int* __restrict__ cols,
                                            const float* __restrict__ vals,
                                            const u32* __restrict__ G,
                                            u32* __restrict__ epckS,
                                            u8* __restrict__ lrowS,
                                            const float* __restrict__ A,
                                            const bf16* __restrict__ Bt,
                                            const float* __restrict__ bias,
                                            bf16* __restrict__ C) {
    __shared__ __attribute__((aligned(16))) char smem[40960];
    int bid = blockIdx.x, tid = threadIdx.x;
    int wid = tid >> 6, lane = tid & 63;

    if (bid < NCHUNK) {
        // ---- scatter part: in-LDS bucket grouping, coalesced write-out ----
        u32* sdat  = (u32*)smem;                 // 16 KB [CHUNK]
        u8*  sbkt  = (u8*)(smem + 16384);        //  4 KB
        u8*  srow  = (u8*)(smem + 20480);        //  4 KB
        u32* h     = (u32*)(smem + 24576);       //  8 KB [8 waves x 256]
        u32* loff  = (u32*)(smem + 32768);       //  1 KB
        u32* lcur  = (u32*)(smem + 33792);       //  1 KB
        u32* gbase = (u32*)(smem + 34816);       //  1 KB
        u32* wt    = (u32*)(smem + 35840);       //  64 B
        int c = bid;
        int base = c * CHUNK;
        int end = base + CHUNK; if (end > N_EDGES) end = N_EDGES;
        int n = end - base;

        for (int i = tid; i < 2048; i += 512) h[i] = 0;

        // global run base per bucket: bucket base + chunk prefix
        u32 tot = 0, pre = 0, incl = 0;
        if (tid < 256) {
            if (tid < NB) {
                for (int cc = 0; cc < NCHUNK; cc++) {
                    u32 v = G[tid * NCHUNK + cc];
                    tot += v;
                    if (cc < c) pre += v;
                }
            }
            incl = tot;
#pragma unroll
            for (int off = 1; off < 64; off <<= 1) {
                u32 u = __shfl_up(incl, off, 64);
                if (lane >= off) incl += u;
            }
            if (lane == 63) wt[wid] = incl;
        }
        __syncthreads();
        if (tid < 256) {
            u32 wpre = 0;
#pragma unroll
            for (int w = 0; w < 4; w++)
                if (w < wid) wpre += wt[w];
            if (tid < NB) gbase[tid] = (wpre + incl - tot) + pre;
        }

        // stage 8 edges/thread in regs + LDS histogram (static idx, rule #20)
        u32 pk_r[8], b_r[8], lr_r[8];
#pragma unroll
        for (int j = 0; j < 8; j++) {
            int e = base + tid + j * 512;
            bool ok = e < end;
            int ee = ok ? e : base;
            int r = rows[ee];
            unsigned short vb = __builtin_bit_cast(unsigned short, (bf16)vals[ee]);
            pk_r[j] = ((u32)cols[ee] << 16) | (u32)vb;
            b_r[j] = (u32)(r >> 8);
            lr_r[j] = (u32)(r & 255);
            if (ok) atomicAdd(&h[wid * 256 + b_r[j]], 1);
        }
        __syncthreads();

        // local exclusive scan over 256 buckets
        u32 t2 = 0, incl2 = 0;
        if (tid < 256) {
#pragma unroll
            for (int w2 = 0; w2 < 8; w2++) t2 += h[w2 * 256 + tid];
            incl2 = t2;
#pragma unroll
            for (int off = 1; off < 64; off <<= 1) {
                u32 u = __shfl_up(incl2, off, 64);
                if (lane >= off) incl2 += u;
            }
            if (lane == 63) wt[wid] = incl2;
        }
        __syncthreads();
        if (tid < 256) {
            u32 wpre2 = 0;
#pragma unroll
            for (int w = 0; w < 4; w++)
                if (w < wid) wpre2 += wt[w];
            u32 excl = wpre2 + incl2 - t2;
            loff[tid] = excl;
            lcur[tid] = excl;
        }
        __syncthreads();

        // place into bucket-grouped LDS
#pragma unroll
        for (int j = 0; j < 8; j++) {
            int e = base + tid + j * 512;
            if (e < end) {
                u32 p = atomicAdd(&lcur[b_r[j]], 1);
                sdat[p] = pk_r[j];
                sbkt[p] = (u8)b_r[j];
                srow[p] = (u8)lr_r[j];
            }
        }
        __syncthreads();

        // coalesced write-out: consecutive i -> consecutive dst within each run
        for (int i = tid; i < n; i += 512) {
            u32 b2 = sbkt[i];
            u32 dst = gbase[b2] + (u32)i - loff[b2];
            epckS[dst] = sdat[i];
            lrowS[dst] = srow[i];
        }
        return;
    }

    // ---- gemm1 part: BM=64, BN=256, BK=64, XOR-swizzled LDS (R18 proven) ----
    constexpr int BM = 64, BK = 64;
    bf16* As = (bf16*)smem;            //  8 KB
    bf16* Bs = (bf16*)(smem + 8192);   // 32 KB
    int l15 = lane & 15, hi = lane >> 4;
    int sw = l15 & 7;
    int bm = bid - NCHUNK;

    f32x4 acc[4][2];
#pragma unroll
    for (int m = 0; m < 4; m++)
#pragma unroll
        for (int n = 0; n < 2; n++) acc[m][n] = (f32x4){0.f, 0.f, 0.f, 0.f};

    for (int kt = 0; kt < F_IN; kt += BK) {
#pragma unroll
        for (int j = 0; j < 4; j++) {
            int ch = j * 512 + tid;
            int row = ch >> 3, kc = ch & 7;
            int kcs = kc ^ (row & 7);
            gl_lds16(Bt + (size_t)row * F_IN + kt + kcs * 8,
                     &Bs[(j * 512 + wid * 64) * 8]);
        }
        {
            int row = tid >> 3, kc = tid & 7;
            int ar = bm * BM + row;
            if (ar >= N_NODES) ar = N_NODES - 1;
            const f32x4* src = (const f32x4*)(A + (size_t)ar * F_IN + kt + kc * 8);
            f32x4 u = src[0], v = src[1];
            bf16x8 o;
            o[0] = (bf16)u[0]; o[1] = (bf16)u[1]; o[2] = (bf16)u[2]; o[3] = (bf16)u[3];
            o[4] = (bf16)v[0]; o[5] = (bf16)v[1]; o[6] = (bf16)v[2]; o[7] = (bf16)v[3];
            *(bf16x8*)&As[row * BK + (kc ^ (row & 7)) * 8] = o;
        }
        __syncthreads();

        bf16x8 afr[2][4], bfr[2][2];
#pragma unroll
        for (int kk = 0; kk < 2; kk++) {
            int c = (kk * 4 + hi) ^ sw;
#pragma unroll
            for (int m = 0; m < 4; m++)
                afr[kk][m] = *(const bf16x8*)&As[(m * 16 + l15) * BK + c * 8];
#pragma unroll
            for (int n = 0; n < 2; n++)
                bfr[kk][n] = *(const bf16x8*)&Bs[(wid * 32 + n * 16 + l15) * BK + c * 8];
        }
#pragma unroll
        for (int kk = 0; kk < 2; kk++)
#pragma unroll
            for (int m = 0; m < 4; m++)
#pragma unroll
                for (int n = 0; n < 2; n++)
                    acc[m][n] = __builtin_amdgcn_mfma_f32_16x16x32_bf16(
                        afr[kk][m], bfr[kk][n], acc[m][n], 0, 0, 0);
        __syncthreads();
    }

#pragma unroll
    for (int m = 0; m < 4; m++) {
        int row0 = bm * BM + m * 16 + hi * 4;
#pragma unroll
        for (int n = 0; n < 2; n++) {
            int col = wid * 32 + n * 16 + l15;
            float bz = bias[col];
#pragma unroll
            for (int r = 0; r < 4; r++) {
                int row = row0 + r;
                if (row < N_NODES)
                    C[(size_t)row * H_DIM + col] = (bf16)(acc[m][n][r] + bz);
            }
        }
    }
}

// ---------------- sortC: in-LDS counting sort within bucket; staged -> final epack ----------------

__global__ __launch_bounds__(256) void sortC_k(const u32* __restrict__ epckS,
                                               const u8* __restrict__ lrowS,
                                               const u32* __restrict__ G,
                                               u32* __restrict__ epack,
                                               int* __restrict__ starts) {
    __shared__ u32 edat[BCAP];
    __shared__ u32 sdat[BCAP];
    __shared__ u8  erow[BCAP];
    __shared__ u32 h[4 * 256];
    __shared__ u32 cur[256];
    __shared__ u32 wt1[4], wt2[4];
    __shared__ u32 sh_s, sh_n;
    int b = blockIdx.x, tid = threadIdx.x, wid = tid >> 6, lane = tid & 63;

    u32 btot = 0;
    if (tid < NB)
        for (int cc = 0; cc < NCHUNK; cc++) btot += G[tid * NCHUNK + cc];
    u32 bincl = btot;
#pragma unroll
    for (int off = 1; off < 64; off <<= 1) {
        u32 u = __shfl_up(bincl, off, 64);
        if (lane >= off) bincl += u;
    }
    if (lane == 63) wt1[wid] = bincl;
    __syncthreads();
    u32 bwpre = 0;
#pragma unroll
    for (int w = 0; w < 4; w++)
        if (w < wid) bwpre += wt1[w];
    if (tid == b) { sh_s = bwpre + bincl - btot; sh_n = btot; }
    __syncthreads();
    int s = (int)sh_s;
    int n = (int)sh_n;
    if (n > BCAP) n = BCAP;

    for (int i = tid; i < n; i += 256) { edat[i] = epckS[s + i]; erow[i] = lrowS[s + i]; }
    for (int i = tid; i < 1024; i += 256) h[i] = 0;
    __syncthreads();
    for (int i = tid; i < n; i += 256) atomicAdd(&h[wid * 256 + erow[i]], 1);
    __syncthreads();
    u32 tot = h[tid] + h[256 + tid] + h[512 + tid] + h[768 + tid];
    u32 incl = tot;
#pragma unroll
    for (int off = 1; off < 64; off <<= 1) {
        u32 u = __shfl_up(incl, off, 64);
        if (lane >= off) incl += u;
    }
    if (lane == 63) wt2[wid] = incl;
    __syncthreads();
    u32 wpre = 0;
#pragma unroll
    for (int w = 0; w < 4; w++)
        if (w < wid) wpre += wt2[w];
    u32 excl = wpre + incl - tot;
    cur[tid] = excl;
    int grow = b * 256 + tid;
    if (grow < N_NODES) starts[grow] = s + (int)excl;
    if (b == 0 && tid == 0) starts[N_NODES] = N_EDGES;
    __syncthreads();
    for (int i = tid; i < n; i += 256) {
        u32 p = atomicAdd(&cur[erow[i]], 1);
        sdat[p] = edat[i];
    }
    __syncthreads();
    for (int i = tid; i < n; i += 256) epack[s + i] = sdat[i];
}

// ---------------- GEMM2: C[M,64] = x16[M,256] @ W2t^T + b2, XOR-swizzled LDS ----------------

__global__ __launch_bounds__(256) void gemm2_k(const bf16* __restrict__ A,
                                               const bf16* __restrict__ Bt,
                                               const float* __restrict__ bias,
                                               bf16* __restrict__ C) {
    constexpr int BM = 128, BK = 64;
    __shared__ bf16 As[BM * BK];
    __shared__ bf16 Bs[64 * BK];

    int tid = threadIdx.x;
    int wid = tid >> 6, lane = tid & 63;
    int wr = wid >> 1, wc = wid & 1;
    int l15 = lane & 15, hi = lane >> 4;
    int sw = l15 & 7;
    int bm = blockIdx.x;

    f32x4 acc[4][2];
#pragma unroll
    for (int m = 0; m < 4; m++)
#pragma unroll
        for (int n = 0; n < 2; n++) acc[m][n] = (f32x4){0.f, 0.f, 0.f, 0.f};

    for (int kt = 0; kt < H_DIM; kt += BK) {
#pragma unroll
        for (int j = 0; j < 4; j++) {
            int ch = j * 256 + tid;
            int row = ch >> 3, kc = ch & 7;
            int kcs = kc ^ (row & 7);
            gl_lds16(A + (size_t)(bm * BM + row) * H_DIM + kt + kcs * 8,
                     &As[(j * 256 + wid * 64) * 8]);
        }
#pragma unroll
        for (int j = 0; j < 2; j++) {
            int ch = j * 256 + tid;
            int row = ch >> 3, kc = ch & 7;
            int kcs = kc ^ (row & 7);
            gl_lds16(Bt + (size_t)row * H_DIM + kt + kcs * 8,
                     &Bs[(j * 256 + wid * 64) * 8]);
        }
        __syncthreads();

        bf16x8 afr[2][4], bfr[2][2];
#pragma unroll
        for (int kk = 0; kk < 2; kk++) {
            int c = (kk * 4 + hi) ^ sw;
#pragma unroll
            for (int m = 0; m < 4; m++)
                afr[kk][m] = *(const bf16x8*)&As[(wr * 64 + m * 16 + l15) * BK + c * 8];
#pragma unroll
            for (int n = 0; n < 2; n++)
                bfr[kk][n] = *(const bf16x8*)&Bs[(wc * 32 + n * 16 + l15) * BK + c * 8];
        }
#pragma unroll
        for (int kk = 0; kk < 2; kk++)
#pragma unroll
            for (int m = 0; m < 4; m++)
#pragma unroll
                for (int n = 0; n < 2; n++)
                    acc[m][n] = __builtin_amdgcn_mfma_f32_16x16x32_bf16(
                        afr[kk][m], bfr[kk][n], acc[m][n], 0, 0, 0);
        __syncthreads();
    }

#pragma unroll
    for (int m = 0; m < 4; m++) {
        int row0 = bm * BM + wr * 64 + m * 16 + hi * 4;
#pragma unroll
        for (int n = 0; n < 2; n++) {
            int col = wc * 32 + n * 16 + l15;
            float bz = bias[col];
#pragma unroll
            for (int r = 0; r < 4; r++) {
                int row = row0 + r;
                if (row < N_NODES)
                    C[(size_t)row * C_DIM + col] = (bf16)(acc[m][n][r] + bz);
            }
        }
    }
}

// ---------------- SpMM1: row-per-wave, 8 gathers in flight, NT streams ----------------
// Parked at line-BW roofline: 800K edges x 8 lines = 410 MB @ ~6.6 TB/s ~ 62 us.

__global__ __launch_bounds__(256) void spmm1_k(const int* __restrict__ starts,
                                               const u32* __restrict__ epack,
                                               const bf16* __restrict__ s1,
                                               bf16* __restrict__ x16) {
    int wid = threadIdx.x >> 6, lane = threadIdx.x & 63;
    int row = blockIdx.x * 4 + wid;
    if (row >= N_NODES) return;
    int s = starts[row], e = starts[row + 1];
    f32x4 acc = (f32x4){0.f, 0.f, 0.f, 0.f};
    const bf16* s1l = s1 + lane * 4;
    int p = s;
    for (; p + 8 <= e; p += 8) {
        u32 k0 = __builtin_nontemporal_load(epack + p);
        u32 k1 = __builtin_nontemporal_load(epack + p + 1);
        u32 k2 = __builtin_nontemporal_load(epack + p + 2);
        u32 k3 = __builtin_nontemporal_load(epack + p + 3);
        u32 k4 = __builtin_nontemporal_load(epack + p + 4);
        u32 k5 = __builtin_nontemporal_load(epack + p + 5);
        u32 k6 = __builtin_nontemporal_load(epack + p + 6);
        u32 k7 = __builtin_nontemporal_load(epack + p + 7);
        bf16x4 g0 = *(const bf16x4*)(s1l + (size_t)(k0 >> 16) * H_DIM);
        bf16x4 g1 = *(const bf16x4*)(s1l + (size_t)(k1 >> 16) * H_DIM);
        bf16x4 g2 = *(const bf16x4*)(s1l + (size_t)(k2 >> 16) * H_DIM);
        bf16x4 g3 = *(const bf16x4*)(s1l + (size_t)(k3 >> 16) * H_DIM);
        bf16x4 g4 = *(const bf16x4*)(s1l + (size_t)(k4 >> 16) * H_DIM);
        bf16x4 g5 = *(const bf16x4*)(s1l + (size_t)(k5 >> 16) * H_DIM);
        bf16x4 g6 = *(const bf16x4*)(s1l + (size_t)(k6 >> 16) * H_DIM);
        bf16x4 g7 = *(const bf16x4*)(s1l + (size_t)(k7 >> 16) * H_DIM);
        float v0 = unpack_val(k0), v1 = unpack_val(k1), v2 = unpack_val(k2), v3 = unpack_val(k3);
        float v4 = unpack_val(k4), v5 = unpack_val(k5), v6 = unpack_val(k6), v7 = unpack_val(k7);
#pragma unroll
        for (int j = 0; j < 4; j++)
            acc[j] += v0 * (float)g0[j] + v1 * (float)g1[j] +
                      v2 * (float)g2[j] + v3 * (float)g3[j] +
                      v4 * (float)g4[j] + v5 * (float)g5[j] +
                      v6 * (float)g6[j] + v7 * (float)g7[j];
    }
    for (; p < e; ++p) {
        u32 k = __builtin_nontemporal_load(epack + p);
        float v = unpack_val(k);
        bf16x4 g = *(const bf16x4*)(s1l + (size_t)(k >> 16) * H_DIM);
#pragma unroll
        for (int j = 0; j < 4; j++) acc[j] += v * (float)g[j];
    }
    bf16x4 o;
#pragma unroll
    for (int j = 0; j < 4; j++) o[j] = (bf16)fmaxf(acc[j], 0.f);
    u64 bits = __builtin_bit_cast(u64, o);
    __builtin_nontemporal_store(bits, (u64*)(x16 + (size_t)row * H_DIM + lane * 4));
}

// ---------------- SpMM2 + log_softmax fused: D=64, lane = class, 8-wide, NT ----------------

__global__ __launch_bounds__(256) void spmm2_sm_k(const int* __restrict__ starts,
                                                  const u32* __restrict__ epack,
                                                  const bf16* __restrict__ s2,
                                                  float* __restrict__ out) {
    int wid = threadIdx.x >> 6, lane = threadIdx.x & 63;
    int row = blockIdx.x * 4 + wid;
    if (row >= N_NODES) return;
    int s = starts[row], e = starts[row + 1];
    float acc = 0.f;
    int p = s;
    for (; p + 8 <= e; p += 8) {
        u32 k0 = __builtin_nontemporal_load(epack + p);
        u32 k1 = __builtin_nontemporal_load(epack + p + 1);
        u32 k2 = __builtin_nontemporal_load(epack + p + 2);
        u32 k3 = __builtin_nontemporal_load(epack + p + 3);
        u32 k4 = __builtin_nontemporal_load(epack + p + 4);
        u32 k5 = __builtin_nontemporal_load(epack + p + 5);
        u32 k6 = __builtin_nontemporal_load(epack + p + 6);
        u32 k7 = __builtin_nontemporal_load(epack + p + 7);
        float g0 = (float)s2[(size_t)(k0 >> 16) * C_DIM + lane];
        float g1 = (float)s2[(size_t)(k1 >> 16) * C_DIM + lane];
        float g2 = (float)s2[(size_t)(k2 >> 16) * C_DIM + lane];
        float g3 = (float)s2[(size_t)(k3 >> 16) * C_DIM + lane];
        float g4 = (float)s2[(size_t)(k4 >> 16) * C_DIM + lane];
        float g5 = (float)s2[(size_t)(k5 >> 16) * C_DIM + lane];
        float g6 = (float)s2[(size_t)(k6 >> 16) * C_DIM + lane];
        float g7 = (float)s2[(size_t)(k7 >> 16) * C_DIM + lane];
        acc += unpack_val(k0) * g0 + unpack_val(k1) * g1 +
               unpack_val(k2) * g2 + unpack_val(k3) * g3 +
               unpack_val(k4) * g4 + unpack_val(k5) * g5 +
               unpack_val(k6) * g6 + unpack_val(k7) * g7;
    }
    for (; p < e; ++p) {
        u32 k = __builtin_nontemporal_load(epack + p);
        acc += unpack_val(k) * (float)s2[(size_t)(k >> 16) * C_DIM + lane];
    }
    float mx = acc;
#pragma unroll
    for (int off = 32; off >= 1; off >>= 1) mx = fmaxf(mx, __shfl_xor(mx, off, 64));
    float ex = expf(acc - mx);
    float se = ex;
#pragma unroll
    for (int off = 32; off >= 1; off >>= 1) se += __shfl_xor(se, off, 64);
    __builtin_nontemporal_store((acc - mx) - logf(se),
                                out + (size_t)row * C_DIM + lane);
}

// ---------------- launch ----------------

extern "C" void kernel_launch(void* const* d_in, const int* in_sizes, int n_in,
                              void* d_out, int out_size, void* d_ws, size_t ws_size,
                              hipStream_t stream) {
    const float* nf   = (const float*)d_in[0];
    const int*   rows = (const int*)d_in[1];
    const int*   cols = (const int*)d_in[2];
    const float* vals = (const float*)d_in[3];
    const float* W1   = (const float*)d_in[4];
    const float* b1   = (const float*)d_in[5];
    const float* W2   = (const float*)d_in[6];
    const float* b2   = (const float*)d_in[7];
    float* out = (float*)d_out;

    char* w = (char*)d_ws;
    auto alloc = [&](size_t b) { void* p = (void*)w; w += (b + 255) & ~(size_t)255; return p; };

    bf16* x16  = (bf16*)alloc((size_t)MPAD * H_DIM * 2);
    bf16* sup1 = (bf16*)alloc((size_t)N_NODES * H_DIM * 2);
    bf16* sup2 = sup1;   // aliases sup1 (dead by then)
    bf16* W1t = (bf16*)alloc((size_t)H_DIM * F_IN * 2);
    bf16* W2t = (bf16*)alloc((size_t)C_DIM * H_DIM * 2);
    int* starts = (int*)alloc((size_t)(N_NODES + 1) * 4);
    u32* G      = (u32*)alloc((size_t)NB * NCHUNK * 4);
    u32* epack  = (u32*)alloc((size_t)N_EDGES * 4);
    u32* epckS  = (u32*)alloc((size_t)N_EDGES * 4);
    u8*  lrowS  = (u8*)alloc((size_t)N_EDGES);

    // 1) hist + weight transpose (independent, fused)
    prep_k<<<NCHUNK + 144, 1024, 0, stream>>>(rows, W1, W2, G, W1t, W2t);
    // 2) scatter (196 blocks, LDS-grouped coalesced writes) + layer-1 GEMM (782 blocks)
    sg_k<<<NCHUNK + MPAD / 64, 512, 0, stream>>>(rows, cols, vals, G, epckS, lrowS,
                                                 nf, W1t, b1, sup1);
    // 3) in-bucket sort (staged -> sorted final epack)
    sortC_k<<<NB, 256, 0, stream>>>(epckS, lrowS, G, epack, starts);
    // 4) aggregate layer 1
    spmm1_k<<<(N_NODES + 3) / 4, 256, 0, stream>>>(starts, epack, sup1, x16);
    // 5) layer 2 GEMM (swizzled LDS)
    gemm2_k<<<MPAD / 128, 256, 0, stream>>>(x16, W2t, b2, sup2);
    // 6) aggregate layer 2 + log_softmax
    spmm2_sm_k<<<(N_NODES + 3) / 4, 256, 0, stream>>>(starts, epack, sup2, out);

    (void)in_sizes; (void)n_in; (void)out_size; (void)ws_size;
}

// Round 20
// 164.146 us; speedup vs baseline: 1.1179x; 1.0128x over previous
//
#include <hip/hip_runtime.h>

#define N_NODES 50000
#define N_EDGES 800000
#define F_IN    512
#define H_DIM   256
#define C_DIM   64
#define MPAD    50048   // 782 * 64

// sort geometry: bucket = row >> 8 (256 rows/bucket), chunk = 4096 edges
#define NB      196
#define NCHUNK  196     // ceil(800000/4096)
#define CHUNK   4096
#define BCAP    6144

typedef __bf16 bf16;
typedef __bf16 bf16x4 __attribute__((ext_vector_type(4)));
typedef __bf16 bf16x8 __attribute__((ext_vector_type(8)));
typedef float  f32x4  __attribute__((ext_vector_type(4)));
typedef unsigned int u32;
typedef unsigned long long u64;
typedef unsigned char u8;

__device__ __forceinline__ void gl_lds16(const void* g, void* l) {
    __builtin_amdgcn_global_load_lds(
        (const __attribute__((address_space(1))) u32*)g,
        (__attribute__((address_space(3))) u32*)l, 16, 0, 0);
}

__device__ __forceinline__ float unpack_val(u32 pk) {
    return __builtin_bit_cast(float, pk << 16);
}

// ---------------- prep: edge histogram (blocks 0..NCHUNK-1) + weight transpose ----------------

__global__ __launch_bounds__(1024) void prep_k(const int* __restrict__ rows,
                                               const float* __restrict__ W1,
                                               const float* __restrict__ W2,
                                               u32* __restrict__ G,
                                               bf16* __restrict__ W1t,
                                               bf16* __restrict__ W2t) {
    __shared__ u32 h[16 * NB];
    int bid = blockIdx.x, tid = threadIdx.x;
    if (bid < NCHUNK) {
        int wid = tid >> 6;
        for (int i = tid; i < 16 * NB; i += 1024) h[i] = 0;
        __syncthreads();
        int base = bid * CHUNK;
        int end = base + CHUNK; if (end > N_EDGES) end = N_EDGES;
        for (int e = base + tid; e < end; e += 1024)
            atomicAdd(&h[wid * NB + (rows[e] >> 8)], 1);
        __syncthreads();
        if (tid < NB) {
            u32 s = 0;
#pragma unroll
            for (int w = 0; w < 16; w++) s += h[w * NB + tid];
            G[tid * NCHUNK + bid] = s;
        }
    } else {
        int i = (bid - NCHUNK) * 1024 + tid;   // 144 blocks cover 147456 elems
        if (i < F_IN * H_DIM) {
            int k = i >> 8, n = i & 255;
            W1t[n * F_IN + k] = (bf16)W1[i];
        } else {
            int j = i - F_IN * H_DIM;
            if (j < H_DIM * C_DIM) {
                int k = j >> 6, n = j & 63;
                W2t[n * H_DIM + k] = (bf16)W2[j];
            }
        }
    }
}

// ---------------- scat_k: standalone LDS-grouped scatter, coalesced write-out ----------------

__global__ __launch_bounds__(1024) void scat_k(const int* __restrict__ rows,
                                               const int* __restrict__ cols,
                                               const float* __restrict__ vals,
                                               const u32* __restrict__ G,
                                               u32* __restrict__ epckS,
                                               u8* __restrict__ lrowS) {
    __shared__ u32 sdat[CHUNK];          // 16 KB
    __shared__ u8  sbkt[CHUNK];          //  4 KB
    __shared__ u8  srow[CHUNK];          //  4 KB
    __shared__ u32 h[16 * 256];          // 16 KB
    __shared__ u32 loff[256], lcur[256], gbase[256];
    __shared__ u32 wt[16];
    int tid = threadIdx.x, wid = tid >> 6, lane = tid & 63;
    int c = blockIdx.x;
    int base = c * CHUNK;
    int end = base + CHUNK; if (end > N_EDGES) end = N_EDGES;
    int n = end - base;

    for (int i = tid; i < 4096; i += 1024) h[i] = 0;

    // global run base per bucket: bucket base + chunk prefix (threads 0..255)
    u32 tot = 0, pre = 0, incl = 0;
    if (tid < 256) {
        if (tid < NB) {
            for (int cc = 0; cc < NCHUNK; cc++) {
                u32 v = G[tid * NCHUNK + cc];
                tot += v;
                if (cc < c) pre += v;
            }
        }
        incl = tot;
#pragma unroll
        for (int off = 1; off < 64; off <<= 1) {
            u32 u = __shfl_up(incl, off, 64);
            if (lane >= off) incl += u;
        }
        if (lane == 63) wt[wid] = incl;
    }
    __syncthreads();
    if (tid < 256) {
        u32 wpre = 0;
#pragma unroll
        for (int w = 0; w < 4; w++)
            if (w < wid) wpre += wt[w];
        if (tid < NB) gbase[tid] = (wpre + incl - tot) + pre;
    }

    // stage 4 edges/thread in regs + LDS histogram
    u32 pk_r[4], b_r[4], lr_r[4];
#pragma unroll
    for (int j = 0; j < 4; j++) {
        int e = base + tid + j * 1024;
        bool ok = e < end;
        int ee = ok ? e : base;
        int r = rows[ee];
        unsigned short vb = __builtin_bit_cast(unsigned short, (bf16)vals[ee]);
        pk_r[j] = ((u32)cols[ee] << 16) | (u32)vb;
        b_r[j] = (u32)(r >> 8);
        lr_r[j] = (u32)(r & 255);
        if (ok) atomicAdd(&h[wid * 256 + b_r[j]], 1);
    }
    __syncthreads();

    // local exclusive scan over 256 buckets (threads 0..255 over 16 slabs)
    u32 t2 = 0, incl2 = 0;
    if (tid < 256) {
#pragma unroll
        for (int w2 = 0; w2 < 16; w2++) t2 += h[w2 * 256 + tid];
        incl2 = t2;
#pragma unroll
        for (int off = 1; off < 64; off <<= 1) {
            u32 u = __shfl_up(incl2, off, 64);
            if (lane >= off) incl2 += u;
        }
        if (lane == 63) wt[wid] = incl2;
    }
    __syncthreads();
    if (tid < 256) {
        u32 wpre2 = 0;
#pragma unroll
        for (int w = 0; w < 4; w++)
            if (w < wid) wpre2 += wt[w];
        u32 excl = wpre2 + incl2 - t2;
        loff[tid] = excl;
        lcur[tid] = excl;
    }
    __syncthreads();

    // place into bucket-grouped LDS
#pragma unroll
    for (int j = 0; j < 4; j++) {
        int e = base + tid + j * 1024;
        if (e < end) {
            u32 p = atomicAdd(&lcur[b_r[j]], 1);
            sdat[p] = pk_r[j];
            sbkt[p] = (u8)b_r[j];
            srow[p] = (u8)lr_r[j];
        }
    }
    __syncthreads();

    // coalesced write-out
    for (int i = tid; i < n; i += 1024) {
        u32 b2 = sbkt[i];
        u32 dst = gbase[b2] + (u32)i - loff[b2];
        epckS[dst] = sdat[i];
        lrowS[dst] = srow[i];
    }
}

// ---------------- sg2_k: sortC (blocks 0..NB-1) + GEMM1 (blocks NB..) merged ----------------
// Sort: 512 thr, 40KB LDS (no edat copy; re-reads epckS from L2).
// GEMM1: BM=64, BN=256, BK=64, XOR-swizzled LDS (R18 proven).

__global__ __launch_bounds__(512) void sg2_k(const u32* __restrict__ epckS,
                                             const u8* __restrict__ lrowS,
                                             const u32* __restrict__ G,
                                             u32* __restrict__ epack,
                                             int* __restrict__ starts,
                                             const float* __restrict__ A,
                                             const bf16* __restrict__ Bt,
                                             const float* __restrict__ bias,
                                             bf16* __restrict__ C) {
    __shared__ __attribute__((aligned(16))) char smem[40960];
    int bid = blockIdx.x, tid = threadIdx.x;
    int wid = tid >> 6, lane = tid & 63;

    if (bid < NB) {
        // ---- sort part (512 threads) ----
        u32* sdat = (u32*)smem;                  // 24576 B [BCAP]
        u8*  erow = (u8*)(smem + 24576);         //  6144 B [BCAP]
        u32* h    = (u32*)(smem + 30720);        //  8192 B [8 x 256]
        u32* cur  = (u32*)(smem + 38912);        //  1024 B
        u32* wt1  = (u32*)(smem + 39936);        //    16 B
        u32* shsn = (u32*)(smem + 39952);        //     8 B
        int b = bid;

        u32 btot = 0, bincl = 0;
        if (tid < 256) {
            if (tid < NB)
                for (int cc = 0; cc < NCHUNK; cc++) btot += G[tid * NCHUNK + cc];
            bincl = btot;
#pragma unroll
            for (int off = 1; off < 64; off <<= 1) {
                u32 u = __shfl_up(bincl, off, 64);
                if (lane >= off) bincl += u;
            }
            if (lane == 63) wt1[wid] = bincl;
        }
        __syncthreads();
        if (tid < 256) {
            u32 bwpre = 0;
#pragma unroll
            for (int w = 0; w < 4; w++)
                if (w < wid) bwpre += wt1[w];
            if (tid == b) { shsn[0] = bwpre + bincl - btot; shsn[1] = btot; }
        }
        __syncthreads();
        int s = (int)shsn[0];
        int n = (int)shsn[1];
        if (n > BCAP) n = BCAP;

        for (int i = tid; i < 2048; i += 512) h[i] = 0;
        __syncthreads();
        for (int i = tid; i < n; i += 512) {
            u8 r = lrowS[s + i];
            erow[i] = r;
            atomicAdd(&h[wid * 256 + r], 1);
        }
        __syncthreads();
        u32 tot = 0, incl = 0;
        if (tid < 256) {
#pragma unroll
            for (int w = 0; w < 8; w++) tot += h[w * 256 + tid];
            incl = tot;
#pragma unroll
            for (int off = 1; off < 64; off <<= 1) {
                u32 u = __shfl_up(incl, off, 64);
                if (lane >= off) incl += u;
            }
            if (lane == 63) wt1[wid] = incl;
        }
        __syncthreads();
        if (tid < 256) {
            u32 wpre = 0;
#pragma unroll
            for (int w = 0; w < 4; w++)
                if (w < wid) wpre += wt1[w];
            u32 excl = wpre + incl - tot;
            cur[tid] = excl;
            int grow = b * 256 + tid;
            if (grow < N_NODES) starts[grow] = s + (int)excl;
        }
        if (b == 0 && tid == 0) starts[N_NODES] = N_EDGES;
        __syncthreads();
        for (int i = tid; i < n; i += 512) {
            u32 v = epckS[s + i];
            u32 p = atomicAdd(&cur[erow[i]], 1);
            sdat[p] = v;
        }
        __syncthreads();
        for (int i = tid; i < n; i += 512) epack[s + i] = sdat[i];
        return;
    }

    // ---- gemm1 part: BM=64, BN=256, BK=64, XOR-swizzled LDS ----
    constexpr int BM = 64, BK = 64;
    bf16* As = (bf16*)smem;            //  8 KB
    bf16* Bs = (bf16*)(smem + 8192);   // 32 KB
    int l15 = lane & 15, hi = lane >> 4;
    int sw = l15 & 7;
    int bm = bid - NB;

    f32x4 acc[4][2];
#pragma unroll
    for (int m = 0; m < 4; m++)
#pragma unroll
        for (int n = 0; n < 2; n++) acc[m][n] = (f32x4){0.f, 0.f, 0.f, 0.f};

    for (int kt = 0; kt < F_IN; kt += BK) {
#pragma unroll
        for (int j = 0; j < 4; j++) {
            int ch = j * 512 + tid;
            int row = ch >> 3, kc = ch & 7;
            int kcs = kc ^ (row & 7);
            gl_lds16(Bt + (size_t)row * F_IN + kt + kcs * 8,
                     &Bs[(j * 512 + wid * 64) * 8]);
        }
        {
            int row = tid >> 3, kc = tid & 7;
            int ar = bm * BM + row;
            if (ar >= N_NODES) ar = N_NODES - 1;
            const f32x4* src = (const f32x4*)(A + (size_t)ar * F_IN + kt + kc * 8);
            f32x4 u = src[0], v = src[1];
            bf16x8 o;
            o[0] = (bf16)u[0]; o[1] = (bf16)u[1]; o[2] = (bf16)u[2]; o[3] = (bf16)u[3];
            o[4] = (bf16)v[0]; o[5] = (bf16)v[1]; o[6] = (bf16)v[2]; o[7] = (bf16)v[3];
            *(bf16x8*)&As[row * BK + (kc ^ (row & 7)) * 8] = o;
        }
        __syncthreads();

        bf16x8 afr[2][4], bfr[2][2];
#pragma unroll
        for (int kk = 0; kk < 2; kk++) {
            int c = (kk * 4 + hi) ^ sw;
#pragma unroll
            for (int m = 0; m < 4; m++)
                afr[kk][m] = *(const bf16x8*)&As[(m * 16 + l15) * BK + c * 8];
#pragma unroll
            for (int n = 0; n < 2; n++)
                bfr[kk][n] = *(const bf16x8*)&Bs[(wid * 32 + n * 16 + l15) * BK + c * 8];
        }
#pragma unroll
        for (int kk = 0; kk < 2; kk++)
#pragma unroll
            for (int m = 0; m < 4; m++)
#pragma unroll
                for (int n = 0; n < 2; n++)
                    acc[m][n] = __builtin_amdgcn_mfma_f32_16x16x32_bf16(
                        afr[kk][m], bfr[kk][n], acc[m][n], 0, 0, 0);
        __syncthreads();
    }

#pragma unroll
    for (int m = 0; m < 4; m++) {
        int row0 = bm * BM + m * 16 + hi * 4;
#pragma unroll
        for (int n = 0; n < 2; n++) {
            int col = wid * 32 + n * 16 + l15;
            float bz = bias[col];
#pragma unroll
            for (int r = 0; r < 4; r++) {
                int row = row0 + r;
                if (row < N_NODES)
                    C[(size_t)row * H_DIM + col] = (bf16)(acc[m][n][r] + bz);
            }
        }
    }
}

// ---------------- GEMM2: C[M,64] = x16[M,256] @ W2t^T + b2, XOR-swizzled LDS ----------------

__global__ __launch_bounds__(256) void gemm2_k(const bf16* __restrict__ A,
                                               const bf16* __restrict__ Bt,
                                               const float* __restrict__ bias,
                                               bf16* __restrict__ C) {
    constexpr int BM = 128, BK = 64;
    __shared__ bf16 As[BM * BK];
    __shared__ bf16 Bs[64 * BK];

    int tid = threadIdx.x;
    int wid = tid >> 6, lane = tid & 63;
    int wr = wid >> 1, wc = wid & 1;
    int l15 = lane & 15, hi = lane >> 4;
    int sw = l15 & 7;
    int bm = blockIdx.x;

    f32x4 acc[4][2];
#pragma unroll
    for (int m = 0; m < 4; m++)
#pragma unroll
        for (int n = 0; n < 2; n++) acc[m][n] = (f32x4){0.f, 0.f, 0.f, 0.f};

    for (int kt = 0; kt < H_DIM; kt += BK) {
#pragma unroll
        for (int j = 0; j < 4; j++) {
            int ch = j * 256 + tid;
            int row = ch >> 3, kc = ch & 7;
            int kcs = kc ^ (row & 7);
            gl_lds16(A + (size_t)(bm * BM + row) * H_DIM + kt + kcs * 8,
                     &As[(j * 256 + wid * 64) * 8]);
        }
#pragma unroll
        for (int j = 0; j < 2; j++) {
            int ch = j * 256 + tid;
            int row = ch >> 3, kc = ch & 7;
            int kcs = kc ^ (row & 7);
            gl_lds16(Bt + (size_t)row * H_DIM + kt + kcs * 8,
                     &Bs[(j * 256 + wid * 64) * 8]);
        }
        __syncthreads();

        bf16x8 afr[2][4], bfr[2][2];
#pragma unroll
        for (int kk = 0; kk < 2; kk++) {
            int c = (kk * 4 + hi) ^ sw;
#pragma unroll
            for (int m = 0; m < 4; m++)
                afr[kk][m] = *(const bf16x8*)&As[(wr * 64 + m * 16 + l15) * BK + c * 8];
#pragma unroll
            for (int n = 0; n < 2; n++)
                bfr[kk][n] = *(const bf16x8*)&Bs[(wc * 32 + n * 16 + l15) * BK + c * 8];
        }
#pragma unroll
        for (int kk = 0; kk < 2; kk++)
#pragma unroll
            for (int m = 0; m < 4; m++)
#pragma unroll
                for (int n = 0; n < 2; n++)
                    acc[m][n] = __builtin_amdgcn_mfma_f32_16x16x32_bf16(
                        afr[kk][m], bfr[kk][n], acc[m][n], 0, 0, 0);
        __syncthreads();
    }

#pragma unroll
    for (int m = 0; m < 4; m++) {
        int row0 = bm * BM + wr * 64 + m * 16 + hi * 4;
#pragma unroll
        for (int n = 0; n < 2; n++) {
            int col = wc * 32 + n * 16 + l15;
            float bz = bias[col];
#pragma unroll
            for (int r = 0; r < 4; r++) {
                int row = row0 + r;
                if (row < N_NODES)
                    C[(size_t)row * C_DIM + col] = (bf16)(acc[m][n][r] + bz);
            }
        }
    }
}

// ---------------- SpMM1: row-per-wave, 8 gathers in flight, NT streams ----------------
// Parked at line-BW roofline: 800K edges x 8 lines = 410 MB @ ~6.6 TB/s ~ 62 us.

__global__ __launch_bounds__(256) void spmm1_k(const int* __restrict__ starts,
                                               const u32* __restrict__ epack,
                                               const bf16* __restrict__ s1,
                                               bf16* __restrict__ x16) {
    int wid = threadIdx.x >> 6, lane = threadIdx.x & 63;
    int row = blockIdx.x * 4 + wid;
    if (row >= N_NODES) return;
    int s = starts[row], e = starts[row + 1];
    f32x4 acc = (f32x4){0.f, 0.f, 0.f, 0.f};
    const bf16* s1l = s1 + lane * 4;
    int p = s;
    for (; p + 8 <= e; p += 8) {
        u32 k0 = __builtin_nontemporal_load(epack + p);
        u32 k1 = __builtin_nontemporal_load(epack + p + 1);
        u32 k2 = __builtin_nontemporal_load(epack + p + 2);
        u32 k3 = __builtin_nontemporal_load(epack + p + 3);
        u32 k4 = __builtin_nontemporal_load(epack + p + 4);
        u32 k5 = __builtin_nontemporal_load(epack + p + 5);
        u32 k6 = __builtin_nontemporal_load(epack + p + 6);
        u32 k7 = __builtin_nontemporal_load(epack + p + 7);
        bf16x4 g0 = *(const bf16x4*)(s1l + (size_t)(k0 >> 16) * H_DIM);
        bf16x4 g1 = *(const bf16x4*)(s1l + (size_t)(k1 >> 16) * H_DIM);
        bf16x4 g2 = *(const bf16x4*)(s1l + (size_t)(k2 >> 16) * H_DIM);
        bf16x4 g3 = *(const bf16x4*)(s1l + (size_t)(k3 >> 16) * H_DIM);
        bf16x4 g4 = *(const bf16x4*)(s1l + (size_t)(k4 >> 16) * H_DIM);
        bf16x4 g5 = *(const bf16x4*)(s1l + (size_t)(k5 >> 16) * H_DIM);
        bf16x4 g6 = *(const bf16x4*)(s1l + (size_t)(k6 >> 16) * H_DIM);
        bf16x4 g7 = *(const bf16x4*)(s1l + (size_t)(k7 >> 16) * H_DIM);
        float v0 = unpack_val(k0), v1 = unpack_val(k1), v2 = unpack_val(k2), v3 = unpack_val(k3);
        float v4 = unpack_val(k4), v5 = unpack_val(k5), v6 = unpack_val(k6), v7 = unpack_val(k7);
#pragma unroll
        for (int j = 0; j < 4; j++)
            acc[j] += v0 * (float)g0[j] + v1 * (float)g1[j] +
                      v2 * (float)g2[j] + v3 * (float)g3[j] +
                      v4 * (float)g4[j] + v5 * (float)g5[j] +
                      v6 * (float)g6[j] + v7 * (float)g7[j];
    }
    for (; p < e; ++p) {
        u32 k = __builtin_nontemporal_load(epack + p);
        float v = unpack_val(k);
        bf16x4 g = *(const bf16x4*)(s1l + (size_t)(k >> 16) * H_DIM);
#pragma unroll
        for (int j = 0; j < 4; j++) acc[j] += v * (float)g[j];
    }
    bf16x4 o;
#pragma unroll
    for (int j = 0; j < 4; j++) o[j] = (bf16)fmaxf(acc[j], 0.f);
    u64 bits = __builtin_bit_cast(u64, o);
    __builtin_nontemporal_store(bits, (u64*)(x16 + (size_t)row * H_DIM + lane * 4));
}

// ---------------- SpMM2 + log_softmax fused: D=64, lane = class, 8-wide, NT ----------------

__global__ __launch_bounds__(256) void spmm2_sm_k(const int* __restrict__ starts,
                                                  const u32* __restrict__ epack,
                                                  const bf16* __restrict__ s2,
                                                  float* __restrict__ out) {
    int wid = threadIdx.x >> 6, lane = threadIdx.x & 63;
    int row = blockIdx.x * 4 + wid;
    if (row >= N_NODES) return;
    int s = starts[row], e = starts[row + 1];
    float acc = 0.f;
    int p = s;
    for (; p + 8 <= e; p += 8) {
        u32 k0 = __builtin_nontemporal_load(epack + p);
        u32 k1 = __builtin_nontemporal_load(epack + p + 1);
        u32 k2 = __builtin_nontemporal_load(epack + p + 2);
        u32 k3 = __builtin_nontemporal_load(epack + p + 3);
        u32 k4 = __builtin_nontemporal_load(epack + p + 4);
        u32 k5 = __builtin_nontemporal_load(epack + p + 5);
        u32 k6 = __builtin_nontemporal_load(epack + p + 6);
        u32 k7 = __builtin_nontemporal_load(epack + p + 7);
        float g0 = (float)s2[(size_t)(k0 >> 16) * C_DIM + lane];
        float g1 = (float)s2[(size_t)(k1 >> 16) * C_DIM + lane];
        float g2 = (float)s2[(size_t)(k2 >> 16) * C_DIM + lane];
        float g3 = (float)s2[(size_t)(k3 >> 16) * C_DIM + lane];
        float g4 = (float)s2[(size_t)(k4 >> 16) * C_DIM + lane];
        float g5 = (float)s2[(size_t)(k5 >> 16) * C_DIM + lane];
        float g6 = (float)s2[(size_t)(k6 >> 16) * C_DIM + lane];
        float g7 = (float)s2[(size_t)(k7 >> 16) * C_DIM + lane];
        acc += unpack_val(k0) * g0 + unpack_val(k1) * g1 +
               unpack_val(k2) * g2 + unpack_val(k3) * g3 +
               unpack_val(k4) * g4 + unpack_val(k5) * g5 +
               unpack_val(k6) * g6 + unpack_val(k7) * g7;
    }
    for (; p < e; ++p) {
        u32 k = __builtin_nontemporal_load(epack + p);
        acc += unpack_val(k) * (float)s2[(size_t)(k >> 16) * C_DIM + lane];
    }
    float mx = acc;
#pragma unroll
    for (int off = 32; off >= 1; off >>= 1) mx = fmaxf(mx, __shfl_xor(mx, off, 64));
    float ex = expf(acc - mx);
    float se = ex;
#pragma unroll
    for (int off = 32; off >= 1; off >>= 1) se += __shfl_xor(se, off, 64);
    __builtin_nontemporal_store((acc - mx) - logf(se),
                                out + (size_t)row * C_DIM + lane);
}

// ---------------- launch ----------------

extern "C" void kernel_launch(void* const* d_in, const int* in_sizes, int n_in,
                              void* d_out, int out_size, void* d_ws, size_t ws_size,
                              hipStream_t stream) {
    const float* nf   = (const float*)d_in[0];
    const int*   rows = (const int*)d_in[1];
    const int*   cols = (const int*)d_in[2];
    const float* vals = (const float*)d_in[3];
    const float* W1   = (const float*)d_in[4];
    const float* b1   = (const float*)d_in[5];
    const float* W2   = (const float*)d_in[6];
    const float* b2   = (const float*)d_in[7];
    float* out = (float*)d_out;

    char* w = (char*)d_ws;
    auto alloc = [&](size_t b) { void* p = (void*)w; w += (b + 255) & ~(size_t)255; return p; };

    bf16* x16  = (bf16*)alloc((size_t)MPAD * H_DIM * 2);
    bf16* sup1 = (bf16*)alloc((size_t)N_NODES * H_DIM * 2);
    bf16* sup2 = sup1;   // aliases sup1 (dead by then)
    bf16* W1t = (bf16*)alloc((size_t)H_DIM * F_IN * 2);
    bf16* W2t = (bf16*)alloc((size_t)C_DIM * H_DIM * 2);
    int* starts = (int*)alloc((size_t)(N_NODES + 1) * 4);
    u32* G      = (u32*)alloc((size_t)NB * NCHUNK * 4);
    u32* epack  = (u32*)alloc((size_t)N_EDGES * 4);
    u32* epckS  = (u32*)alloc((size_t)N_EDGES * 4);
    u8*  lrowS  = (u8*)alloc((size_t)N_EDGES);

    // 1) hist + weight transpose (independent, fused)
    prep_k<<<NCHUNK + 144, 1024, 0, stream>>>(rows, W1, W2, G, W1t, W2t);
    // 2) standalone scatter (196 blocks x 1024 thr, coalesced writes)
    scat_k<<<NCHUNK, 1024, 0, stream>>>(rows, cols, vals, G, epckS, lrowS);
    // 3) sort (196 blocks) + layer-1 GEMM (782 blocks), co-scheduled
    sg2_k<<<NB + MPAD / 64, 512, 0, stream>>>(epckS, lrowS, G, epack, starts,
                                              nf, W1t, b1, sup1);
    // 4) aggregate layer 1
    spmm1_k<<<(N_NODES + 3) / 4, 256, 0, stream>>>(starts, epack, sup1, x16);
    // 5) layer 2 GEMM (swizzled LDS)
    gemm2_k<<<MPAD / 128, 256, 0, stream>>>(x16, W2t, b2, sup2);
    // 6) aggregate layer 2 + log_softmax
    spmm2_sm_k<<<(N_NODES + 3) / 4, 256, 0, stream>>>(starts, epack, sup2, out);

    (void)in_sizes; (void)n_in; (void)out_size; (void)ws_size;
}